// Round 5
// baseline (287.709 us; speedup 1.0000x reference)
//
#include <hip/hip_runtime.h>
#include <math.h>

// ---------------------------------------------------------------------------
// SSHConv3D fused, round 5: full MFMA reformulation (f16 in, f32 accum).
// Constants: K=5, MD=3, HH=16, CIN=16, F=32, D=48, NJ=2.
//
// Per block: one 32-voxel group (vy 0..7, vz 0..3) at fixed gx=blockIdx.x.
// Stage 1 (conv):  Z[u][vox] = sum_k atoms[u][k] x[k][vox], K = 25 rows x 8 taps
//                  (13 x mfma_32x32x16_f16 per channel; B-frag = one b128 row read)
// Stage 2 (mix):   Y[f][vox] = sum_{c,j} W_n Z  per part (2 K-chunks via LDS Z2)
//                  + central 1x1x1 MFMA on part14; squares -> spec frags
// Stage 3 (proj):  out[fo][vox] = relu(sum_i pw[i] spec[i] + obase)  (K=128)
//
// ws layout (bytes):
//   [0,     13312) atomfrag : f16[t 13][lane 64][j 8]
//   [13312, 21504) wfrag    : f16[n 4][q 2][lane 64][j 8]
//   [21504, 29696) pwfrag   : f16[q 8][lane 64][j 8]
//   [29696, 30720) cwfrag   : f16[lane 64][j 8]
//   [30720, 30848) obase    : f32[32] = proj_b + proj_w . spec_bias
//
// LDS (65536 B exactly):
//   [0,     24576) xtile : f16[c 16][lz 8][ly 12][lx 8]   (rows = 16B, aligned)
//   [24576, 57344) z2    : f16[part 16][soct 4][vox 32][8]
//   [57344, 65536) spec  : f16[vox 32][128], XOR-swizzled; rows 0..3 timeshare xc
//
// part map: p0,p1=(1,1)h3 re/im; p2,p3=(2,1)h7; p4,p5=(2,2)h8; p6=(1,0)h2;
//           p7=(2,0)h6; p8,p9=(3,1)h13; p10,p11=(3,2)h14; p12,p13=(3,3)h15;
//           p14=(0,0)h0 (+central+cb); p15=(3,0)h12.
// wave0: degrees 1,2 (p0..7); wave1: degrees 0,3 (p8..15). No cross-wave merge.
// ---------------------------------------------------------------------------

typedef _Float16 f16;
typedef __attribute__((ext_vector_type(8)))  _Float16 f16x8;
typedef __attribute__((ext_vector_type(16))) float    f32x16;
#define MFMA16 __builtin_amdgcn_mfma_f32_32x32x16_f16

#define ATF_B 0
#define WTF_B 13312
#define PWF_B 21504
#define CWF_B 29696
#define OB_B  30720

__global__ __launch_bounds__(256) void ssh_init(
    const float* __restrict__ w, const float* __restrict__ cw,
    const float* __restrict__ proj_w, const float* __restrict__ spec_bias,
    const float* __restrict__ proj_b, char* __restrict__ wsb)
{
    __shared__ float shr[125][16];
    __shared__ float shi[125][16];
    __shared__ float prof[125][2];
    __shared__ float norms[2][16];
    const int tid = threadIdx.x;
    const float fourpi = 4.0f * 3.14159265358979323846f;

    for (int p = tid; p < 125; p += 256) {
        int d2 = p % 5, d1 = (p / 5) % 5, d0 = p / 25;
        float xc = (float)(d1 - 2), yc = (float)(d0 - 2), zc = (float)(d2 - 2);
        float r2 = xc*xc + yc*yc + zc*zc;
        float r  = sqrtf(r2);
        float phi = atan2f(yc, xc);
        float ct = (r > 0.f) ? (zc / r) : 0.f;
        float st = sqrtf(fmaxf(0.f, 1.f - ct*ct));
        float c1 = cosf(phi), s1 = sinf(phi);
        float c2 = c1*c1 - s1*s1, s2 = 2.f*s1*c1;
        float c3 = c2*c1 - s2*s1, s3 = s2*c1 + c2*s1;
        float P10 = ct,              P11 = -st;
        float P20 = 0.5f*(3.f*ct*ct - 1.f), P21 = -3.f*ct*st, P22 = 3.f*st*st;
        float P30 = 0.5f*(5.f*ct*ct*ct - 3.f*ct);
        float P31 = -1.5f*(5.f*ct*ct - 1.f)*st;
        float P32 = 15.f*ct*st*st;
        float P33 = -15.f*st*st*st;
        float N00 = sqrtf(1.f/fourpi);
        float N10 = sqrtf(3.f/fourpi);
        float N11 = sqrtf(3.f/fourpi * 0.5f);
        float N20 = sqrtf(5.f/fourpi);
        float N21 = sqrtf(5.f/fourpi / 6.f);
        float N22 = sqrtf(5.f/fourpi / 24.f);
        float N30 = sqrtf(7.f/fourpi);
        float N31 = sqrtf(7.f/fourpi / 12.f);
        float N32 = sqrtf(7.f/fourpi / 120.f);
        float N33 = sqrtf(7.f/fourpi / 720.f);
        float b;
        shr[p][0] = N00;               shi[p][0] = 0.f;
        shr[p][2] = N10*P10;           shi[p][2] = 0.f;
        b = N11*P11;
        shr[p][3] =  b*c1;             shi[p][3] =  b*s1;
        shr[p][1] = -b*c1;             shi[p][1] =  b*s1;
        shr[p][6] = N20*P20;           shi[p][6] = 0.f;
        b = N21*P21;
        shr[p][7] =  b*c1;             shi[p][7] =  b*s1;
        shr[p][5] = -b*c1;             shi[p][5] =  b*s1;
        b = N22*P22;
        shr[p][8] =  b*c2;             shi[p][8] =  b*s2;
        shr[p][4] =  b*c2;             shi[p][4] = -b*s2;
        shr[p][12] = N30*P30;          shi[p][12] = 0.f;
        b = N31*P31;
        shr[p][13] =  b*c1;            shi[p][13] =  b*s1;
        shr[p][11] = -b*c1;            shi[p][11] =  b*s1;
        b = N32*P32;
        shr[p][14] =  b*c2;            shi[p][14] =  b*s2;
        shr[p][10] =  b*c2;            shi[p][10] = -b*s2;
        b = N33*P33;
        shr[p][15] =  b*c3;            shi[p][15] =  b*s3;
        shr[p][9]  = -b*c3;            shi[p][9]  =  b*s3;
        prof[p][0] = fmaxf(0.f, 1.f - fabsf(r - 1.f));
        prof[p][1] = fmaxf(0.f, 1.f - fabsf(r - 2.f));
    }
    __syncthreads();

    if (tid < 32) {
        int j = tid >> 4, h = tid & 15;
        float acc = 0.f;
        for (int p = 0; p < 125; ++p) {
            float pr = prof[p][j];
            acc += pr*pr*(shr[p][h]*shr[p][h] + shi[p][h]*shi[p][h]);
        }
        float nn = sqrtf(acc);
        norms[j][h] = (nn > 0.f) ? nn : 1.f;
    }
    __syncthreads();

    const int hmap[16] = {3,3, 7,7, 8,8, 2, 6, 13,13, 14,14, 15,15, 0, 12};
    const int imfl[16] = {0,1, 0,1, 0,1, 0, 0, 0,1, 0,1, 0,1, 0, 0};

    // atomfrag[t][lane][j]
    for (int idx = tid; idx < 13*64*8; idx += 256) {
        int j = idx & 7, l = (idx >> 3) & 63, t = idx >> 9;
        int oct = l >> 5, u = l & 31, part = u & 15, j2 = u >> 4;
        int row = 2*t + oct;
        float val = 0.f;
        if (row < 25 && j < 5) {
            int p = (row/5)*25 + (row%5)*5 + j;
            int h = hmap[part];
            float base = prof[p][j2] / norms[j2][h];
            val = base * (imfl[part] ? shi[p][h] : shr[p][h]);
        }
        ((f16*)(wsb + ATF_B))[idx] = (f16)val;
    }
    // wfrag[n][q][lane][j]
    for (int idx = tid; idx < 4096; idx += 256) {
        int j = idx & 7, l = (idx >> 3) & 63, q = (idx >> 9) & 1, n = idx >> 10;
        int s = (2*q + (l>>5))*8 + j, c = s >> 1, j2 = s & 1, f = l & 31;
        ((f16*)(wsb + WTF_B))[idx] = (f16)w[((c*32 + f)*2 + j2)*4 + n];
    }
    // pwfrag[q][lane][j]
    for (int idx = tid; idx < 4096; idx += 256) {
        int j = idx & 7, l = (idx >> 3) & 63, q = idx >> 9;
        int i = (2*q + (l>>5))*8 + j, fo = l & 31;
        ((f16*)(wsb + PWF_B))[idx] = (f16)proj_w[fo*128 + i];
    }
    // cwfrag[lane][j]
    for (int idx = tid; idx < 512; idx += 256) {
        int j = idx & 7, l = idx >> 3;
        int f = l & 31, c = (l>>5)*8 + j;
        ((f16*)(wsb + CWF_B))[idx] = (f16)cw[f*16 + c];
    }
    if (tid < 32) {
        float acc = proj_b[tid];
        for (int i = 0; i < 128; ++i) acc += proj_w[tid*128 + i] * spec_bias[i];
        ((float*)(wsb + OB_B))[tid] = acc;
    }
}

__global__ __launch_bounds__(128) void ssh_main(
    const float* __restrict__ x, const float* __restrict__ cb,
    const char* __restrict__ wsb, float* __restrict__ out)
{
    __shared__ __align__(16) char lds[65536];
    f16* xt = (f16*)lds;              // [c][lz 8][ly 12][lx 8] ; pitches 768/96/8
    f16* z2 = (f16*)(lds + 24576);    // [part][soct 4][vox 32][8] ; 1024/256/8
    f16* sp = (f16*)(lds + 57344);    // [vox][128]

    const int tid = threadIdx.x;
    const int bx2 = blockIdx.x, Y0 = blockIdx.y*8, Z0 = blockIdx.z*4;
    const int lane = tid & 63, w = tid >> 6;
    const int vox = lane & 31, oct = lane >> 5;
    const int vy = vox & 7, vz = vox >> 3;

    // ---- preload fragments (global, L2-hot)
    const f16x8* atf = (const f16x8*)(wsb + ATF_B);
    const f16x8* wtf = (const f16x8*)(wsb + WTF_B);
    const f16x8* pwf = (const f16x8*)(wsb + PWF_B);
    const f16x8* cwf = (const f16x8*)(wsb + CWF_B);
    const float* obase = (const float*)(wsb + OB_B);

    f16x8 A[13];
#pragma unroll
    for (int t = 0; t < 13; ++t) A[t] = atf[t*64 + lane];
    // wave's mixing weights: w0: WA=n1, WB=n2 ; w1: WA=n3, WB=n0
    f16x8 WA0, WA1, WB0, WB1;
    if (w == 0) {
        WA0 = wtf[1*128 + 0*64 + lane]; WA1 = wtf[1*128 + 1*64 + lane];
        WB0 = wtf[2*128 + 0*64 + lane]; WB1 = wtf[2*128 + 1*64 + lane];
    } else {
        WA0 = wtf[3*128 + 0*64 + lane]; WA1 = wtf[3*128 + 1*64 + lane];
        WB0 = wtf[0*128 + 0*64 + lane]; WB1 = wtf[0*128 + 1*64 + lane];
    }

    // ---- stage x -> f16 LDS tile  [c][lz][ly][lx<8], taps beyond dx=+2 zeroed
    for (int i = tid; i < 12288; i += 128) {
        int lx = i & 7; int t1 = i >> 3;
        int ly = t1 % 12; t1 /= 12;
        int lz = t1 & 7; int c = t1 >> 3;
        int gx = bx2 - 2 + lx, gy = Y0 - 2 + ly, gz = Z0 - 2 + lz;
        float v = 0.f;
        if (lx < 5 && (unsigned)gx < 48u && (unsigned)gy < 48u && (unsigned)gz < 48u)
            v = x[((c*48 + gz)*48 + gy)*48 + gx];
        xt[c*768 + lz*96 + ly*8 + lx] = (f16)v;
    }
    // xc (central-pixel channels) timeshares spec rows 0..3: sp[vox*128 + c]
    for (int i = tid; i < 512; i += 128) {
        int v2 = i & 31, c = i >> 5;
        int gy = Y0 + (v2 & 7), gz = Z0 + (v2 >> 3);
        sp[v2*128 + c] = (f16)x[((c*48 + gz)*48 + gy)*48 + bx2];
    }
    __syncthreads();

    // ---- per-lane stage-1 read offsets (halves), one per K-step
    int off[13];
#pragma unroll
    for (int t = 0; t < 13; ++t) {
        int row = 2*t + oct; if (row > 24) row = 0;   // pad row: zero coefs
        int d0 = row / 5, d1 = row % 5;
        off[t] = (vz + d0)*96 + (vy + d1)*8;
    }

    // ---- stage 1: conv GEMMs, 2 channels in flight for ILP
#pragma unroll 1
    for (int cp = 0; cp < 4; ++cp) {
        int cA = w*8 + cp*2, cB = cA + 1;
        const f16* bA = xt + cA*768;
        const f16* bB = xt + cB*768;
        f32x16 zA = 0.f, zB = 0.f;
#pragma unroll
        for (int t = 0; t < 13; ++t) {
            f16x8 xA = *(const f16x8*)(bA + off[t]);
            f16x8 xB = *(const f16x8*)(bB + off[t]);
            zA = MFMA16(A[t], xA, zA, 0, 0, 0);
            zB = MFMA16(A[t], xB, zB, 0, 0, 0);
        }
        // D layout: col=vox=lane&31, row u=(reg&3)+8*(reg>>2)+4*oct  (m74/m101)
#pragma unroll
        for (int r = 0; r < 16; ++r) {
            int u = (r & 3) + 8*(r >> 2) + 4*oct;
            int part = u & 15, j2 = u >> 4;
            int sA = cA*2 + j2, sB = cB*2 + j2;
            z2[part*1024 + (sA >> 3)*256 + vox*8 + (sA & 7)] = (f16)zA[r];
            z2[part*1024 + (sB >> 3)*256 + vox*8 + (sB & 7)] = (f16)zB[r];
        }
    }
    __syncthreads();

    // ---- stage 2: mixing + power spectrum (per-wave degrees)
#define ZR(p, q) (*(const f16x8*)(z2 + (p)*1024 + (2*(q) + oct)*256 + vox*8))
    f32x16 sA = 0.f, sB = 0.f;   // w0: sA=n1,sB=n2 ; w1: sA=n3,sB=n0
    if (w == 0) {
        f32x16 yr, yi, y;
        // ci0 = h3 (n=1), parts 0,1
        yr = MFMA16(WA0, ZR(0,0), (f32x16)0.f, 0,0,0);
        yr = MFMA16(WA1, ZR(0,1), yr, 0,0,0);
        yi = MFMA16(WA0, ZR(1,0), (f32x16)0.f, 0,0,0);
        yi = MFMA16(WA1, ZR(1,1), yi, 0,0,0);
#pragma unroll
        for (int r = 0; r < 16; ++r) sA[r] += (yr[r]*yr[r] + yi[r]*yi[r])*(2.f/3.f);
        // r1 = h2 (n=1), part 6
        y = MFMA16(WA0, ZR(6,0), (f32x16)0.f, 0,0,0);
        y = MFMA16(WA1, ZR(6,1), y, 0,0,0);
#pragma unroll
        for (int r = 0; r < 16; ++r) sA[r] += y[r]*y[r]*(1.f/3.f);
        // ci1 = h7 (n=2), parts 2,3
        yr = MFMA16(WB0, ZR(2,0), (f32x16)0.f, 0,0,0);
        yr = MFMA16(WB1, ZR(2,1), yr, 0,0,0);
        yi = MFMA16(WB0, ZR(3,0), (f32x16)0.f, 0,0,0);
        yi = MFMA16(WB1, ZR(3,1), yi, 0,0,0);
#pragma unroll
        for (int r = 0; r < 16; ++r) sB[r] += (yr[r]*yr[r] + yi[r]*yi[r])*(2.f/5.f);
        // ci2 = h8 (n=2), parts 4,5
        yr = MFMA16(WB0, ZR(4,0), (f32x16)0.f, 0,0,0);
        yr = MFMA16(WB1, ZR(4,1), yr, 0,0,0);
        yi = MFMA16(WB0, ZR(5,0), (f32x16)0.f, 0,0,0);
        yi = MFMA16(WB1, ZR(5,1), yi, 0,0,0);
#pragma unroll
        for (int r = 0; r < 16; ++r) sB[r] += (yr[r]*yr[r] + yi[r]*yi[r])*(2.f/5.f);
        // r2 = h6 (n=2), part 7
        y = MFMA16(WB0, ZR(7,0), (f32x16)0.f, 0,0,0);
        y = MFMA16(WB1, ZR(7,1), y, 0,0,0);
#pragma unroll
        for (int r = 0; r < 16; ++r) sB[r] += y[r]*y[r]*(1.f/5.f);
    } else {
        f32x16 yr, yi, y;
        // ci3 = h13 (n=3), parts 8,9
        yr = MFMA16(WA0, ZR(8,0), (f32x16)0.f, 0,0,0);
        yr = MFMA16(WA1, ZR(8,1), yr, 0,0,0);
        yi = MFMA16(WA0, ZR(9,0), (f32x16)0.f, 0,0,0);
        yi = MFMA16(WA1, ZR(9,1), yi, 0,0,0);
#pragma unroll
        for (int r = 0; r < 16; ++r) sA[r] += (yr[r]*yr[r] + yi[r]*yi[r])*(2.f/7.f);
        // ci4 = h14 (n=3), parts 10,11
        yr = MFMA16(WA0, ZR(10,0), (f32x16)0.f, 0,0,0);
        yr = MFMA16(WA1, ZR(10,1), yr, 0,0,0);
        yi = MFMA16(WA0, ZR(11,0), (f32x16)0.f, 0,0,0);
        yi = MFMA16(WA1, ZR(11,1), yi, 0,0,0);
#pragma unroll
        for (int r = 0; r < 16; ++r) sA[r] += (yr[r]*yr[r] + yi[r]*yi[r])*(2.f/7.f);
        // ci5 = h15 (n=3), parts 12,13
        yr = MFMA16(WA0, ZR(12,0), (f32x16)0.f, 0,0,0);
        yr = MFMA16(WA1, ZR(12,1), yr, 0,0,0);
        yi = MFMA16(WA0, ZR(13,0), (f32x16)0.f, 0,0,0);
        yi = MFMA16(WA1, ZR(13,1), yi, 0,0,0);
#pragma unroll
        for (int r = 0; r < 16; ++r) sA[r] += (yr[r]*yr[r] + yi[r]*yi[r])*(2.f/7.f);
        // r3 = h12 (n=3), part 15
        y = MFMA16(WA0, ZR(15,0), (f32x16)0.f, 0,0,0);
        y = MFMA16(WA1, ZR(15,1), y, 0,0,0);
#pragma unroll
        for (int r = 0; r < 16; ++r) sA[r] += y[r]*y[r]*(1.f/7.f);
        // r0 = h0 (n=0), part 14: central MFMA + cb, then square
        f16x8 xcf = *(const f16x8*)(sp + vox*128 + oct*8);
        y = MFMA16(cwf[lane], xcf, (f32x16)0.f, 0,0,0);
        y = MFMA16(WB0, ZR(14,0), y, 0,0,0);
        y = MFMA16(WB1, ZR(14,1), y, 0,0,0);
#pragma unroll
        for (int r = 0; r < 16; ++r) {
            int f = (r & 3) + 8*(r >> 2) + 4*oct;
            float t = y[r] + cb[f];
            sB[r] += t*t;
        }
    }
    __syncthreads();   // central consumed; safe to overwrite sp with spec

    // ---- spec writes: slot i = f*4+n, byte = (vox*256 + i*2) ^ ((vox&7)<<4)
    {
        const int nA = (w == 0) ? 1 : 3;
        const int nB = (w == 0) ? 2 : 0;
#pragma unroll
        for (int r = 0; r < 16; ++r) {
            int f = (r & 3) + 8*(r >> 2) + 4*oct;
            int bA_ = (vox*256 + (f*4 + nA)*2) ^ ((vox & 7) << 4);
            int bB_ = (vox*256 + (f*4 + nB)*2) ^ ((vox & 7) << 4);
            *(f16*)(lds + 57344 + bA_) = (f16)sA[r];
            *(f16*)(lds + 57344 + bB_) = (f16)sB[r];
        }
    }
    __syncthreads();

    // ---- stage 3: projection (wave 1 only) + bias + relu + store
    if (w == 1) {
        f32x16 o = 0.f;
#pragma unroll
        for (int q = 0; q < 8; ++q) {
            f16x8 a = pwf[q*64 + lane];
            int byte = (vox*256 + (2*q + oct)*16) ^ ((vox & 7) << 4);
            f16x8 b = *(const f16x8*)(lds + 57344 + byte);
            o = MFMA16(a, b, o, 0, 0, 0);
        }
        const int gy = Y0 + vy, gz = Z0 + vz;
#pragma unroll
        for (int r = 0; r < 16; ++r) {
            int fo = (r & 3) + 8*(r >> 2) + 4*oct;
            float v = o[r] + obase[fo];
            out[((fo*48 + gz)*48 + gy)*48 + bx2] = fmaxf(v, 0.f);
        }
    }
}

extern "C" void kernel_launch(void* const* d_in, const int* in_sizes, int n_in,
                              void* d_out, int out_size, void* d_ws, size_t ws_size,
                              hipStream_t stream) {
    const float* x  = (const float*)d_in[0];
    const float* w  = (const float*)d_in[1];
    const float* cw = (const float*)d_in[2];
    const float* cb = (const float*)d_in[3];
    const float* sb = (const float*)d_in[4];
    const float* pw = (const float*)d_in[5];
    const float* pb = (const float*)d_in[6];
    float* out = (float*)d_out;
    char* wsb = (char*)d_ws;

    ssh_init<<<dim3(1), dim3(256), 0, stream>>>(w, cw, pw, sb, pb, wsb);
    ssh_main<<<dim3(48, 6, 12), dim3(128), 0, stream>>>(x, cb, wsb, out);
}

// Round 6
// 226.092 us; speedup vs baseline: 1.2725x; 1.2725x over previous
//
#include <hip/hip_runtime.h>
#include <math.h>

// ---------------------------------------------------------------------------
// SSHConv3D fused, round 6: MFMA datapath (r5, verified) with occupancy fixes.
//   - LDS 52,224 B -> 3 blocks/CU (was 65,536 -> 2)
//   - z2 split: z2A (parts 0-7) live region; z2B (parts 8-15) reuses dead
//     x-tile region after stage 1 (held in 32 packed-f16 VGPRs meanwhile)
//   - z2 layout [part][vox][s-swizzled]: paired b32 writes, b128 reads
//   - x-tile ly-pitch 13 (bank spread), staging as packed b32
//   - stage 1: 4 independent MFMA chains; stage 3: both waves, stores split
//
// LDS map (bytes):
//   [0,     26624) xtile : f16 idx c*832 + lz*104 + ly*8 + lx  (ly pitch 13)
//   [0,     16384)   ...after stage1 barrier: z2B (parts 8-15)
//   [26624, 43008) z2A   : parts 0-7,  byte p*2048 + vox*64 + chunk^swz*16
//   [43008, 44032) xc    : f16 [vox 32][c 16]
//   [44032, 52224) spec  : f16 [vox][128], XOR-swizzled
//
// ws layout (bytes): unchanged from r5.
// part map: p0,p1=(1,1)h3 re/im; p2,p3=(2,1)h7; p4,p5=(2,2)h8; p6=(1,0)h2;
//           p7=(2,0)h6; p8,p9=(3,1)h13; p10,p11=(3,2)h14; p12,p13=(3,3)h15;
//           p14=(0,0)h0 (+central+cb); p15=(3,0)h12.
// wave0: parts 0-7 (deg 1,2); wave1: parts 8-15 (deg 0,3).
// ---------------------------------------------------------------------------

typedef _Float16 f16;
typedef __attribute__((ext_vector_type(8)))  _Float16 f16x8;
typedef __attribute__((ext_vector_type(16))) float    f32x16;
#define MFMA16 __builtin_amdgcn_mfma_f32_32x32x16_f16

#define ATF_B 0
#define WTF_B 13312
#define PWF_B 21504
#define CWF_B 29696
#define OB_B  30720

#define XT_B  0
#define Z2B_B 0
#define Z2A_B 26624
#define XC_B  43008
#define SP_B  44032
#define LDS_SZ 52224

__global__ __launch_bounds__(256) void ssh_init(
    const float* __restrict__ w, const float* __restrict__ cw,
    const float* __restrict__ proj_w, const float* __restrict__ spec_bias,
    const float* __restrict__ proj_b, char* __restrict__ wsb)
{
    __shared__ float shr[125][16];
    __shared__ float shi[125][16];
    __shared__ float prof[125][2];
    __shared__ float norms[2][16];
    const int tid = threadIdx.x;
    const float fourpi = 4.0f * 3.14159265358979323846f;

    for (int p = tid; p < 125; p += 256) {
        int d2 = p % 5, d1 = (p / 5) % 5, d0 = p / 25;
        float xc = (float)(d1 - 2), yc = (float)(d0 - 2), zc = (float)(d2 - 2);
        float r2 = xc*xc + yc*yc + zc*zc;
        float r  = sqrtf(r2);
        float phi = atan2f(yc, xc);
        float ct = (r > 0.f) ? (zc / r) : 0.f;
        float st = sqrtf(fmaxf(0.f, 1.f - ct*ct));
        float c1 = cosf(phi), s1 = sinf(phi);
        float c2 = c1*c1 - s1*s1, s2 = 2.f*s1*c1;
        float c3 = c2*c1 - s2*s1, s3 = s2*c1 + c2*s1;
        float P10 = ct,              P11 = -st;
        float P20 = 0.5f*(3.f*ct*ct - 1.f), P21 = -3.f*ct*st, P22 = 3.f*st*st;
        float P30 = 0.5f*(5.f*ct*ct*ct - 3.f*ct);
        float P31 = -1.5f*(5.f*ct*ct - 1.f)*st;
        float P32 = 15.f*ct*st*st;
        float P33 = -15.f*st*st*st;
        float N00 = sqrtf(1.f/fourpi);
        float N10 = sqrtf(3.f/fourpi);
        float N11 = sqrtf(3.f/fourpi * 0.5f);
        float N20 = sqrtf(5.f/fourpi);
        float N21 = sqrtf(5.f/fourpi / 6.f);
        float N22 = sqrtf(5.f/fourpi / 24.f);
        float N30 = sqrtf(7.f/fourpi);
        float N31 = sqrtf(7.f/fourpi / 12.f);
        float N32 = sqrtf(7.f/fourpi / 120.f);
        float N33 = sqrtf(7.f/fourpi / 720.f);
        float b;
        shr[p][0] = N00;               shi[p][0] = 0.f;
        shr[p][2] = N10*P10;           shi[p][2] = 0.f;
        b = N11*P11;
        shr[p][3] =  b*c1;             shi[p][3] =  b*s1;
        shr[p][1] = -b*c1;             shi[p][1] =  b*s1;
        shr[p][6] = N20*P20;           shi[p][6] = 0.f;
        b = N21*P21;
        shr[p][7] =  b*c1;             shi[p][7] =  b*s1;
        shr[p][5] = -b*c1;             shi[p][5] =  b*s1;
        b = N22*P22;
        shr[p][8] =  b*c2;             shi[p][8] =  b*s2;
        shr[p][4] =  b*c2;             shi[p][4] = -b*s2;
        shr[p][12] = N30*P30;          shi[p][12] = 0.f;
        b = N31*P31;
        shr[p][13] =  b*c1;            shi[p][13] =  b*s1;
        shr[p][11] = -b*c1;            shi[p][11] =  b*s1;
        b = N32*P32;
        shr[p][14] =  b*c2;            shi[p][14] =  b*s2;
        shr[p][10] =  b*c2;            shi[p][10] = -b*s2;
        b = N33*P33;
        shr[p][15] =  b*c3;            shi[p][15] =  b*s3;
        shr[p][9]  = -b*c3;            shi[p][9]  =  b*s3;
        prof[p][0] = fmaxf(0.f, 1.f - fabsf(r - 1.f));
        prof[p][1] = fmaxf(0.f, 1.f - fabsf(r - 2.f));
    }
    __syncthreads();

    if (tid < 32) {
        int j = tid >> 4, h = tid & 15;
        float acc = 0.f;
        for (int p = 0; p < 125; ++p) {
            float pr = prof[p][j];
            acc += pr*pr*(shr[p][h]*shr[p][h] + shi[p][h]*shi[p][h]);
        }
        float nn = sqrtf(acc);
        norms[j][h] = (nn > 0.f) ? nn : 1.f;
    }
    __syncthreads();

    const int hmap[16] = {3,3, 7,7, 8,8, 2, 6, 13,13, 14,14, 15,15, 0, 12};
    const int imfl[16] = {0,1, 0,1, 0,1, 0, 0, 0,1, 0,1, 0,1, 0, 0};

    // atomfrag[t][lane][j]
    for (int idx = tid; idx < 13*64*8; idx += 256) {
        int j = idx & 7, l = (idx >> 3) & 63, t = idx >> 9;
        int oct = l >> 5, u = l & 31, part = u & 15, j2 = u >> 4;
        int row = 2*t + oct;
        float val = 0.f;
        if (row < 25 && j < 5) {
            int p = (row/5)*25 + (row%5)*5 + j;
            int h = hmap[part];
            float base = prof[p][j2] / norms[j2][h];
            val = base * (imfl[part] ? shi[p][h] : shr[p][h]);
        }
        ((f16*)(wsb + ATF_B))[idx] = (f16)val;
    }
    // wfrag[n][q][lane][j]
    for (int idx = tid; idx < 4096; idx += 256) {
        int j = idx & 7, l = (idx >> 3) & 63, q = (idx >> 9) & 1, n = idx >> 10;
        int s = (2*q + (l>>5))*8 + j, c = s >> 1, j2 = s & 1, f = l & 31;
        ((f16*)(wsb + WTF_B))[idx] = (f16)w[((c*32 + f)*2 + j2)*4 + n];
    }
    // pwfrag[q][lane][j]
    for (int idx = tid; idx < 4096; idx += 256) {
        int j = idx & 7, l = (idx >> 3) & 63, q = idx >> 9;
        int i = (2*q + (l>>5))*8 + j, fo = l & 31;
        ((f16*)(wsb + PWF_B))[idx] = (f16)proj_w[fo*128 + i];
    }
    // cwfrag[lane][j]
    for (int idx = tid; idx < 512; idx += 256) {
        int j = idx & 7, l = idx >> 3;
        int f = l & 31, c = (l>>5)*8 + j;
        ((f16*)(wsb + CWF_B))[idx] = (f16)cw[f*16 + c];
    }
    if (tid < 32) {
        float acc = proj_b[tid];
        for (int i = 0; i < 128; ++i) acc += proj_w[tid*128 + i] * spec_bias[i];
        ((float*)(wsb + OB_B))[tid] = acc;
    }
}

static __device__ __forceinline__ unsigned pk2(float a, float b) {
    union { _Float16 h[2]; unsigned u; } P;
    P.h[0] = (_Float16)a; P.h[1] = (_Float16)b;
    return P.u;
}

__global__ __launch_bounds__(128) void ssh_main(
    const float* __restrict__ x, const float* __restrict__ cb,
    const char* __restrict__ wsb, float* __restrict__ out)
{
    __shared__ __align__(16) char lds[LDS_SZ];

    const int tid = threadIdx.x;
    const int bx2 = blockIdx.x, Y0 = blockIdx.y*8, Z0 = blockIdx.z*4;
    const int lane = tid & 63, w = tid >> 6;
    const int vox = lane & 31, oct = lane >> 5;
    const int vy = vox & 7, vz = vox >> 3;

    const f16x8* atf = (const f16x8*)(wsb + ATF_B);
    const f16x8* wtf = (const f16x8*)(wsb + WTF_B);
    const f16x8* pwf = (const f16x8*)(wsb + PWF_B);
    const f16x8* cwf = (const f16x8*)(wsb + CWF_B);
    const float* obase = (const float*)(wsb + OB_B);

    f16x8 A[13];
#pragma unroll
    for (int t = 0; t < 13; ++t) A[t] = atf[t*64 + lane];
    f16x8 WA0, WA1, WB0, WB1;
    if (w == 0) {
        WA0 = wtf[1*128 + 0*64 + lane]; WA1 = wtf[1*128 + 1*64 + lane];
        WB0 = wtf[2*128 + 0*64 + lane]; WB1 = wtf[2*128 + 1*64 + lane];
    } else {
        WA0 = wtf[3*128 + 0*64 + lane]; WA1 = wtf[3*128 + 1*64 + lane];
        WB0 = wtf[0*128 + 0*64 + lane]; WB1 = wtf[0*128 + 1*64 + lane];
    }

    // ---- stage x -> f16 LDS tile (packed b32 pairs); ly-pitch 13 (pad col unused)
    for (int i = tid; i < 6144; i += 128) {
        int lx2 = i & 3; int t1 = i >> 2;
        int ly = t1 % 12; t1 /= 12;
        int lz = t1 & 7; int c = t1 >> 3;
        int lx = lx2 * 2;
        int gx0 = bx2 - 2 + lx, gy = Y0 - 2 + ly, gz = Z0 - 2 + lz;
        float v0 = 0.f, v1 = 0.f;
        if ((unsigned)gy < 48u && (unsigned)gz < 48u) {
            int base = ((c*48 + gz)*48 + gy)*48;
            if (lx < 5 && (unsigned)gx0 < 48u)           v0 = x[base + gx0];
            if (lx + 1 < 5 && (unsigned)(gx0+1) < 48u)   v1 = x[base + gx0 + 1];
        }
        *(unsigned*)(lds + XT_B + c*1664 + lz*208 + ly*16 + lx*2) = pk2(v0, v1);
    }
    // xc: [vox][16 c]
    for (int i = tid; i < 512; i += 128) {
        int v2 = i & 31, c = i >> 5;
        int gy = Y0 + (v2 & 7), gz = Z0 + (v2 >> 3);
        *(f16*)(lds + XC_B + (v2*16 + c)*2) = (f16)x[((c*48 + gz)*48 + gy)*48 + bx2];
    }
    __syncthreads();

    // ---- per-lane stage-1 read offsets (bytes)
    int off[13];
#pragma unroll
    for (int t = 0; t < 13; ++t) {
        int row = 2*t + oct; if (row > 24) row = 0;   // pad row: zero coefs
        int d0 = row / 5, d1 = row % 5;
        off[t] = (vz + d0)*208 + (vy + d1)*16;
    }

    // ---- stage 1: conv GEMMs, 4 chains; write parts 0-7 to z2A, hold 8-15
    unsigned held[2][4][4];
#pragma unroll
    for (int half = 0; half < 2; ++half) {
        const int c0 = w*8 + half*4;
        const char* b0 = lds + XT_B + (c0+0)*1664;
        const char* b1 = lds + XT_B + (c0+1)*1664;
        const char* b2 = lds + XT_B + (c0+2)*1664;
        const char* b3 = lds + XT_B + (c0+3)*1664;
        f32x16 z0 = 0.f, z1 = 0.f, z2v = 0.f, z3 = 0.f;
#pragma unroll
        for (int t = 0; t < 13; ++t) {
            f16x8 x0 = *(const f16x8*)(b0 + off[t]);
            f16x8 x1 = *(const f16x8*)(b1 + off[t]);
            f16x8 x2 = *(const f16x8*)(b2 + off[t]);
            f16x8 x3 = *(const f16x8*)(b3 + off[t]);
            z0 = MFMA16(A[t], x0, z0, 0, 0, 0);
            z1 = MFMA16(A[t], x1, z1, 0, 0, 0);
            z2v = MFMA16(A[t], x2, z2v, 0, 0, 0);
            z3 = MFMA16(A[t], x3, z3, 0, 0, 0);
        }
#define EMIT(zi, i) do { \
        const int c_ = c0 + (i); \
        char* wb_ = lds + Z2A_B + vox*64 + (((c_>>2) ^ (vox&3))<<4) + ((2*c_)&7)*2; \
        _Pragma("unroll") \
        for (int r = 0; r < 4; ++r) \
            *(unsigned*)(wb_ + (r + 4*oct)*2048) = pk2((zi)[r], (zi)[r+8]); \
        _Pragma("unroll") \
        for (int r = 4; r < 8; ++r) \
            held[half][i][r-4] = pk2((zi)[r], (zi)[r+8]); \
    } while (0)
        EMIT(z0, 0); EMIT(z1, 1); EMIT(z2v, 2); EMIT(z3, 3);
#undef EMIT
    }
    __syncthreads();   // all xtile reads done

    // ---- phase B: dump held parts 8-15 into z2B (reused xtile region)
#pragma unroll
    for (int half = 0; half < 2; ++half)
#pragma unroll
        for (int i = 0; i < 4; ++i) {
            const int c_ = w*8 + half*4 + i;
            char* wb_ = lds + Z2B_B + vox*64 + (((c_>>2) ^ (vox&3))<<4) + ((2*c_)&7)*2;
#pragma unroll
            for (int r = 0; r < 4; ++r)
                *(unsigned*)(wb_ + (r + 4*oct)*2048) = held[half][i][r];
        }
    __syncthreads();

    // ---- stage 2: mixing + power spectrum (per-wave part groups)
    const char* zbase = lds + ((w == 0) ? Z2A_B : Z2B_B);
#define ZR(p, q) (*(const f16x8*)(zbase + ((p)&7)*2048 + vox*64 + (((2*(q) + oct) ^ (vox&3))<<4)))
    f32x16 sA = 0.f, sB = 0.f;   // w0: sA=n1,sB=n2 ; w1: sA=n3,sB=n0
    if (w == 0) {
        f32x16 yr, yi, y;
        yr = MFMA16(WA0, ZR(0,0), (f32x16)0.f, 0,0,0);
        yr = MFMA16(WA1, ZR(0,1), yr, 0,0,0);
        yi = MFMA16(WA0, ZR(1,0), (f32x16)0.f, 0,0,0);
        yi = MFMA16(WA1, ZR(1,1), yi, 0,0,0);
#pragma unroll
        for (int r = 0; r < 16; ++r) sA[r] += (yr[r]*yr[r] + yi[r]*yi[r])*(2.f/3.f);
        y = MFMA16(WA0, ZR(6,0), (f32x16)0.f, 0,0,0);
        y = MFMA16(WA1, ZR(6,1), y, 0,0,0);
#pragma unroll
        for (int r = 0; r < 16; ++r) sA[r] += y[r]*y[r]*(1.f/3.f);
        yr = MFMA16(WB0, ZR(2,0), (f32x16)0.f, 0,0,0);
        yr = MFMA16(WB1, ZR(2,1), yr, 0,0,0);
        yi = MFMA16(WB0, ZR(3,0), (f32x16)0.f, 0,0,0);
        yi = MFMA16(WB1, ZR(3,1), yi, 0,0,0);
#pragma unroll
        for (int r = 0; r < 16; ++r) sB[r] += (yr[r]*yr[r] + yi[r]*yi[r])*(2.f/5.f);
        yr = MFMA16(WB0, ZR(4,0), (f32x16)0.f, 0,0,0);
        yr = MFMA16(WB1, ZR(4,1), yr, 0,0,0);
        yi = MFMA16(WB0, ZR(5,0), (f32x16)0.f, 0,0,0);
        yi = MFMA16(WB1, ZR(5,1), yi, 0,0,0);
#pragma unroll
        for (int r = 0; r < 16; ++r) sB[r] += (yr[r]*yr[r] + yi[r]*yi[r])*(2.f/5.f);
        y = MFMA16(WB0, ZR(7,0), (f32x16)0.f, 0,0,0);
        y = MFMA16(WB1, ZR(7,1), y, 0,0,0);
#pragma unroll
        for (int r = 0; r < 16; ++r) sB[r] += y[r]*y[r]*(1.f/5.f);
    } else {
        f32x16 yr, yi, y;
        yr = MFMA16(WA0, ZR(8,0), (f32x16)0.f, 0,0,0);
        yr = MFMA16(WA1, ZR(8,1), yr, 0,0,0);
        yi = MFMA16(WA0, ZR(9,0), (f32x16)0.f, 0,0,0);
        yi = MFMA16(WA1, ZR(9,1), yi, 0,0,0);
#pragma unroll
        for (int r = 0; r < 16; ++r) sA[r] += (yr[r]*yr[r] + yi[r]*yi[r])*(2.f/7.f);
        yr = MFMA16(WA0, ZR(10,0), (f32x16)0.f, 0,0,0);
        yr = MFMA16(WA1, ZR(10,1), yr, 0,0,0);
        yi = MFMA16(WA0, ZR(11,0), (f32x16)0.f, 0,0,0);
        yi = MFMA16(WA1, ZR(11,1), yi, 0,0,0);
#pragma unroll
        for (int r = 0; r < 16; ++r) sA[r] += (yr[r]*yr[r] + yi[r]*yi[r])*(2.f/7.f);
        yr = MFMA16(WA0, ZR(12,0), (f32x16)0.f, 0,0,0);
        yr = MFMA16(WA1, ZR(12,1), yr, 0,0,0);
        yi = MFMA16(WA0, ZR(13,0), (f32x16)0.f, 0,0,0);
        yi = MFMA16(WA1, ZR(13,1), yi, 0,0,0);
#pragma unroll
        for (int r = 0; r < 16; ++r) sA[r] += (yr[r]*yr[r] + yi[r]*yi[r])*(2.f/7.f);
        y = MFMA16(WA0, ZR(15,0), (f32x16)0.f, 0,0,0);
        y = MFMA16(WA1, ZR(15,1), y, 0,0,0);
#pragma unroll
        for (int r = 0; r < 16; ++r) sA[r] += y[r]*y[r]*(1.f/7.f);
        // part 14: central MFMA + cb, then square (n=0)
        f16x8 xcf = *(const f16x8*)(lds + XC_B + vox*32 + oct*16);
        y = MFMA16(cwf[lane], xcf, (f32x16)0.f, 0,0,0);
        y = MFMA16(WB0, ZR(14,0), y, 0,0,0);
        y = MFMA16(WB1, ZR(14,1), y, 0,0,0);
#pragma unroll
        for (int r = 0; r < 16; ++r) {
            int f = (r & 3) + 8*(r >> 2) + 4*oct;
            float t = y[r] + cb[f];
            sB[r] += t*t;
        }
    }
#undef ZR

    // ---- spec writes: slot i = f*4+n, byte = (vox*256 + i*2) ^ ((vox&7)<<4)
    {
        const int nA = (w == 0) ? 1 : 3;
        const int nB = (w == 0) ? 2 : 0;
#pragma unroll
        for (int r = 0; r < 16; ++r) {
            int f = (r & 3) + 8*(r >> 2) + 4*oct;
            int bA_ = (vox*256 + (f*4 + nA)*2) ^ ((vox & 7) << 4);
            int bB_ = (vox*256 + (f*4 + nB)*2) ^ ((vox & 7) << 4);
            *(f16*)(lds + SP_B + bA_) = (f16)sA[r];
            *(f16*)(lds + SP_B + bB_) = (f16)sB[r];
        }
    }
    __syncthreads();

    // ---- stage 3: projection (both waves; stores split 8/8) + bias + relu
    {
        f32x16 o = 0.f;
#pragma unroll
        for (int q = 0; q < 8; ++q) {
            f16x8 a = pwf[q*64 + lane];
            int byte = (vox*256 + (2*q + oct)*16) ^ ((vox & 7) << 4);
            f16x8 b2 = *(const f16x8*)(lds + SP_B + byte);
            o = MFMA16(a, b2, o, 0, 0, 0);
        }
        const int gy = Y0 + vy, gz = Z0 + vz;
        if (w == 0) {
#pragma unroll
            for (int r = 0; r < 8; ++r) {
                int fo = (r & 3) + 8*(r >> 2) + 4*oct;
                float v = o[r] + obase[fo];
                out[((fo*48 + gz)*48 + gy)*48 + bx2] = fmaxf(v, 0.f);
            }
        } else {
#pragma unroll
            for (int r = 8; r < 16; ++r) {
                int fo = (r & 3) + 8*(r >> 2) + 4*oct;
                float v = o[r] + obase[fo];
                out[((fo*48 + gz)*48 + gy)*48 + bx2] = fmaxf(v, 0.f);
            }
        }
    }
}

extern "C" void kernel_launch(void* const* d_in, const int* in_sizes, int n_in,
                              void* d_out, int out_size, void* d_ws, size_t ws_size,
                              hipStream_t stream) {
    const float* x  = (const float*)d_in[0];
    const float* w  = (const float*)d_in[1];
    const float* cw = (const float*)d_in[2];
    const float* cb = (const float*)d_in[3];
    const float* sb = (const float*)d_in[4];
    const float* pw = (const float*)d_in[5];
    const float* pb = (const float*)d_in[6];
    float* out = (float*)d_out;
    char* wsb = (char*)d_ws;

    ssh_init<<<dim3(1), dim3(256), 0, stream>>>(w, cw, pw, sb, pb, wsb);
    ssh_main<<<dim3(48, 6, 12), dim3(128), 0, stream>>>(x, cb, wsb, out);
}

// Round 7
// 190.821 us; speedup vs baseline: 1.5077x; 1.1848x over previous
//
#include <hip/hip_runtime.h>
#include <hip/hip_fp16.h>
#include <math.h>

// ---------------------------------------------------------------------------
// SSHConv3D fused, round 7: r4 structure (m>=0 symmetry, packed-f16 datapath)
// + conv coefficient tables (atab2, edelta) staged in LDS.
// Rationale: r4's 41% VALU-idle traced to per-e global float4 coef loads in
// the conv inner loops (L1/L2 latency, unroll-2 depth). Coefs are wave-
// uniform -> LDS broadcast reads, batched with the x ds_reads.
//
// ws layout (bytes):
//   [0,     23552) atab2 : h2[16 h][92 e][4] = {(ar0),(ai0),(ar1),(ai1)} repl. pairs
//   [23552, 31744) wT2   : h2[n][f][j][8 cp]
//   [31744, 32768) cw2   : h2[f][8 cp]
//   [32768, 49152) pwT   : f32[(f*4+n)][fo]
//   [49152, 49280) obase : f32[32]
//   [49280, 49648) edelta: int[92] byte offsets (pre-scaled by 48)
//
// LDS (60,784 B -> 2 blocks/CU):
//   [0,     36864) xtile : f16 [pos 768][CPAD 24]  (48B rows, conflict-free)
//   [36864, 60416) atabL : copy of atab2
//   [60416, 60784) edL   : copy of edelta
// lmerge (16,896 B) reuses xtile after conv/mix.
// ---------------------------------------------------------------------------

#define TX 8
#define TY 4
#define TZ 4
#define LXX 12
#define LYY 8
#define LZZ 8
#define NPOS 768
#define CPAD 24
#define POSB 48

#define ATAB2_B 0
#define WT2_B   23552
#define CW2_B   31744
#define PWT_B   32768
#define OB_B    49152
#define ED_B    49280

#define XT_B   0
#define ATL_B  36864
#define EDL_B  60416
#define LDS_SZ 60784

typedef __half2 h2;
union I4H { int4 v; h2 h[4]; };

__global__ __launch_bounds__(256) void ssh_init(
    const float* __restrict__ w, const float* __restrict__ cw,
    const float* __restrict__ proj_w, const float* __restrict__ spec_bias,
    const float* __restrict__ proj_b, char* __restrict__ wsb)
{
    __shared__ float shr[125][16];
    __shared__ float shi[125][16];
    __shared__ float prof[125][2];
    __shared__ float norms[2][16];
    __shared__ int epos[92];
    const int tid = threadIdx.x;
    const float fourpi = 4.0f * 3.14159265358979323846f;

    for (int p = tid; p < 125; p += 256) {
        int d2 = p % 5, d1 = (p / 5) % 5, d0 = p / 25;
        float xc = (float)(d1 - 2), yc = (float)(d0 - 2), zc = (float)(d2 - 2);
        float r2 = xc*xc + yc*yc + zc*zc;
        float r  = sqrtf(r2);
        float phi = atan2f(yc, xc);
        float ct = (r > 0.f) ? (zc / r) : 0.f;
        float st = sqrtf(fmaxf(0.f, 1.f - ct*ct));
        float c1 = cosf(phi), s1 = sinf(phi);
        float c2 = c1*c1 - s1*s1, s2 = 2.f*s1*c1;
        float c3 = c2*c1 - s2*s1, s3 = s2*c1 + c2*s1;
        float P10 = ct,              P11 = -st;
        float P20 = 0.5f*(3.f*ct*ct - 1.f), P21 = -3.f*ct*st, P22 = 3.f*st*st;
        float P30 = 0.5f*(5.f*ct*ct*ct - 3.f*ct);
        float P31 = -1.5f*(5.f*ct*ct - 1.f)*st;
        float P32 = 15.f*ct*st*st;
        float P33 = -15.f*st*st*st;
        float N00 = sqrtf(1.f/fourpi);
        float N10 = sqrtf(3.f/fourpi);
        float N11 = sqrtf(3.f/fourpi * 0.5f);
        float N20 = sqrtf(5.f/fourpi);
        float N21 = sqrtf(5.f/fourpi / 6.f);
        float N22 = sqrtf(5.f/fourpi / 24.f);
        float N30 = sqrtf(7.f/fourpi);
        float N31 = sqrtf(7.f/fourpi / 12.f);
        float N32 = sqrtf(7.f/fourpi / 120.f);
        float N33 = sqrtf(7.f/fourpi / 720.f);
        float b;
        shr[p][0] = N00;               shi[p][0] = 0.f;
        shr[p][2] = N10*P10;           shi[p][2] = 0.f;
        b = N11*P11;
        shr[p][3] =  b*c1;             shi[p][3] =  b*s1;
        shr[p][1] = -b*c1;             shi[p][1] =  b*s1;
        shr[p][6] = N20*P20;           shi[p][6] = 0.f;
        b = N21*P21;
        shr[p][7] =  b*c1;             shi[p][7] =  b*s1;
        shr[p][5] = -b*c1;             shi[p][5] =  b*s1;
        b = N22*P22;
        shr[p][8] =  b*c2;             shi[p][8] =  b*s2;
        shr[p][4] =  b*c2;             shi[p][4] = -b*s2;
        shr[p][12] = N30*P30;          shi[p][12] = 0.f;
        b = N31*P31;
        shr[p][13] =  b*c1;            shi[p][13] =  b*s1;
        shr[p][11] = -b*c1;            shi[p][11] =  b*s1;
        b = N32*P32;
        shr[p][14] =  b*c2;            shi[p][14] =  b*s2;
        shr[p][10] =  b*c2;            shi[p][10] = -b*s2;
        b = N33*P33;
        shr[p][15] =  b*c3;            shi[p][15] =  b*s3;
        shr[p][9]  = -b*c3;            shi[p][9]  =  b*s3;
        prof[p][0] = fmaxf(0.f, 1.f - fabsf(r - 1.f));
        prof[p][1] = fmaxf(0.f, 1.f - fabsf(r - 2.f));
    }
    __syncthreads();

    if (tid < 32) {
        int j = tid >> 4, h = tid & 15;
        float acc = 0.f;
        for (int p = 0; p < 125; ++p) {
            float pr = prof[p][j];
            acc += pr*pr*(shr[p][h]*shr[p][h] + shi[p][h]*shi[p][h]);
        }
        float nn = sqrtf(acc);
        norms[j][h] = (nn > 0.f) ? nn : 1.f;
    }
    // entry ordering via rank (cls0 base 0, cls1 base 6, cls2 base 26)
    if (tid < 125) {
        int p = tid;
        int d2 = p % 5, d1 = (p / 5) % 5, d0 = p / 25;
        int ix = d1 - 2, iy = d0 - 2, iz = d2 - 2;
        int r2i = ix*ix + iy*iy + iz*iz;
        int cls = (r2i == 1) ? 0 : (r2i == 2 || r2i == 3) ? 1
                : (r2i == 4 || r2i == 5 || r2i == 6 || r2i == 8) ? 2 : -1;
        if (cls >= 0) {
            int rank = (cls == 0) ? 0 : (cls == 1) ? 6 : 26;
            for (int q = 0; q < p; ++q) {
                int e2 = q % 5, e1 = (q / 5) % 5, e0 = q / 25;
                int jx = e1 - 2, jy = e0 - 2, jz = e2 - 2;
                int s2i = jx*jx + jy*jy + jz*jz;
                int c2i = (s2i == 1) ? 0 : (s2i == 2 || s2i == 3) ? 1
                       : (s2i == 4 || s2i == 5 || s2i == 6 || s2i == 8) ? 2 : -1;
                rank += (c2i == cls) ? 1 : 0;
            }
            epos[rank] = p;
            ((int*)(wsb + ED_B))[rank] = (d0*(LYY*LXX) + d1*LXX + d2) * POSB;
        }
    }
    __syncthreads();

    h2* at2 = (h2*)(wsb + ATAB2_B);
    for (int t = tid; t < 92*16; t += 256) {
        int e = t >> 4, h = t & 15;
        int p = epos[e];
        float c0 = prof[p][0] / norms[0][h];
        float c1v = prof[p][1] / norms[1][h];
        at2[(h*92+e)*4 + 0] = __float2half2_rn(c0*shr[p][h]);
        at2[(h*92+e)*4 + 1] = __float2half2_rn(c0*shi[p][h]);
        at2[(h*92+e)*4 + 2] = __float2half2_rn(c1v*shr[p][h]);
        at2[(h*92+e)*4 + 3] = __float2half2_rn(c1v*shi[p][h]);
    }
    // wT2: h2 index = n*512 + f*16 + j*8 + cp
    h2* wt2h = (h2*)(wsb + WT2_B);
    for (int t = tid; t < 2048; t += 256) {
        int n = t >> 9, f = (t >> 4) & 31, j = (t >> 3) & 1, cp = t & 7;
        float a = w[((2*cp*32 + f)*2 + j)*4 + n];
        float b = w[(((2*cp+1)*32 + f)*2 + j)*4 + n];
        wt2h[t] = __halves2half2(__float2half(a), __float2half(b));
    }
    // cw2: h2 index = f*8 + cp
    h2* cw2h = (h2*)(wsb + CW2_B);
    for (int t = tid; t < 256; t += 256) {
        int f = t >> 3, cp = t & 7;
        cw2h[t] = __halves2half2(__float2half(cw[f*16 + 2*cp]),
                                 __float2half(cw[f*16 + 2*cp + 1]));
    }
    // pwT f32 [(f*4+n)][fo]
    float* pwT = (float*)(wsb + PWT_B);
    for (int t = tid; t < 4096; t += 256) {
        int i = t >> 5, fo = t & 31;
        pwT[t] = proj_w[fo*128 + i];
    }
    if (tid < 32) {
        float acc = proj_b[tid];
        for (int i = 0; i < 128; ++i) acc += proj_w[tid*128 + i] * spec_bias[i];
        ((float*)(wsb + OB_B))[tid] = acc;
    }
}

// ---------------- conv passes (coef + ed from LDS) ------------------------
// complex z rows: [0]=r_j0, [1]=i_j0, [2]=r_j1, [3]=i_j1

__device__ __forceinline__ void conv2c(const __half* __restrict__ ldsh, int baseb,
    const int4* __restrict__ aA, const int4* __restrict__ aB,
    const int* __restrict__ ed, h2 (&zA)[4][8], h2 (&zB)[4][8])
{
#pragma unroll
    for (int r = 0; r < 4; ++r)
#pragma unroll
        for (int q = 0; q < 8; ++q) { zA[r][q] = __float2half2_rn(0.f); zB[r][q] = __float2half2_rn(0.f); }

#pragma unroll 2
    for (int e = 0; e < 6; ++e) {           // j0 only
        I4H ca, cb_, x0, x1;
        ca.v = aA[e]; cb_.v = aB[e];
        const int4* p = (const int4*)((const char*)ldsh + baseb + ed[e]);
        x0.v = p[0]; x1.v = p[1];
#pragma unroll
        for (int q = 0; q < 4; ++q) {
            zA[0][q]   = __hfma2(ca.h[0],  x0.h[q], zA[0][q]);
            zA[1][q]   = __hfma2(ca.h[1],  x0.h[q], zA[1][q]);
            zB[0][q]   = __hfma2(cb_.h[0], x0.h[q], zB[0][q]);
            zB[1][q]   = __hfma2(cb_.h[1], x0.h[q], zB[1][q]);
            zA[0][q+4] = __hfma2(ca.h[0],  x1.h[q], zA[0][q+4]);
            zA[1][q+4] = __hfma2(ca.h[1],  x1.h[q], zA[1][q+4]);
            zB[0][q+4] = __hfma2(cb_.h[0], x1.h[q], zB[0][q+4]);
            zB[1][q+4] = __hfma2(cb_.h[1], x1.h[q], zB[1][q+4]);
        }
    }
#pragma unroll 2
    for (int e = 6; e < 26; ++e) {          // both j
        I4H ca, cb_, x0, x1;
        ca.v = aA[e]; cb_.v = aB[e];
        const int4* p = (const int4*)((const char*)ldsh + baseb + ed[e]);
        x0.v = p[0]; x1.v = p[1];
#pragma unroll
        for (int q = 0; q < 4; ++q) {
            zA[0][q]   = __hfma2(ca.h[0],  x0.h[q], zA[0][q]);
            zA[1][q]   = __hfma2(ca.h[1],  x0.h[q], zA[1][q]);
            zA[2][q]   = __hfma2(ca.h[2],  x0.h[q], zA[2][q]);
            zA[3][q]   = __hfma2(ca.h[3],  x0.h[q], zA[3][q]);
            zB[0][q]   = __hfma2(cb_.h[0], x0.h[q], zB[0][q]);
            zB[1][q]   = __hfma2(cb_.h[1], x0.h[q], zB[1][q]);
            zB[2][q]   = __hfma2(cb_.h[2], x0.h[q], zB[2][q]);
            zB[3][q]   = __hfma2(cb_.h[3], x0.h[q], zB[3][q]);
            zA[0][q+4] = __hfma2(ca.h[0],  x1.h[q], zA[0][q+4]);
            zA[1][q+4] = __hfma2(ca.h[1],  x1.h[q], zA[1][q+4]);
            zA[2][q+4] = __hfma2(ca.h[2],  x1.h[q], zA[2][q+4]);
            zA[3][q+4] = __hfma2(ca.h[3],  x1.h[q], zA[3][q+4]);
            zB[0][q+4] = __hfma2(cb_.h[0], x1.h[q], zB[0][q+4]);
            zB[1][q+4] = __hfma2(cb_.h[1], x1.h[q], zB[1][q+4]);
            zB[2][q+4] = __hfma2(cb_.h[2], x1.h[q], zB[2][q+4]);
            zB[3][q+4] = __hfma2(cb_.h[3], x1.h[q], zB[3][q+4]);
        }
    }
#pragma unroll 2
    for (int e = 26; e < 92; ++e) {         // j1 only
        I4H ca, cb_, x0, x1;
        ca.v = aA[e]; cb_.v = aB[e];
        const int4* p = (const int4*)((const char*)ldsh + baseb + ed[e]);
        x0.v = p[0]; x1.v = p[1];
#pragma unroll
        for (int q = 0; q < 4; ++q) {
            zA[2][q]   = __hfma2(ca.h[2],  x0.h[q], zA[2][q]);
            zA[3][q]   = __hfma2(ca.h[3],  x0.h[q], zA[3][q]);
            zB[2][q]   = __hfma2(cb_.h[2], x0.h[q], zB[2][q]);
            zB[3][q]   = __hfma2(cb_.h[3], x0.h[q], zB[3][q]);
            zA[2][q+4] = __hfma2(ca.h[2],  x1.h[q], zA[2][q+4]);
            zA[3][q+4] = __hfma2(ca.h[3],  x1.h[q], zA[3][q+4]);
            zB[2][q+4] = __hfma2(cb_.h[2], x1.h[q], zB[2][q+4]);
            zB[3][q+4] = __hfma2(cb_.h[3], x1.h[q], zB[3][q+4]);
        }
    }
}

__device__ __forceinline__ void conv1c(const __half* __restrict__ ldsh, int baseb,
    const int4* __restrict__ aA, const int* __restrict__ ed, h2 (&zA)[4][8])
{
#pragma unroll
    for (int r = 0; r < 4; ++r)
#pragma unroll
        for (int q = 0; q < 8; ++q) zA[r][q] = __float2half2_rn(0.f);

#pragma unroll 2
    for (int e = 0; e < 6; ++e) {
        I4H ca, x0, x1;
        ca.v = aA[e];
        const int4* p = (const int4*)((const char*)ldsh + baseb + ed[e]);
        x0.v = p[0]; x1.v = p[1];
#pragma unroll
        for (int q = 0; q < 4; ++q) {
            zA[0][q]   = __hfma2(ca.h[0], x0.h[q], zA[0][q]);
            zA[1][q]   = __hfma2(ca.h[1], x0.h[q], zA[1][q]);
            zA[0][q+4] = __hfma2(ca.h[0], x1.h[q], zA[0][q+4]);
            zA[1][q+4] = __hfma2(ca.h[1], x1.h[q], zA[1][q+4]);
        }
    }
#pragma unroll 2
    for (int e = 6; e < 26; ++e) {
        I4H ca, x0, x1;
        ca.v = aA[e];
        const int4* p = (const int4*)((const char*)ldsh + baseb + ed[e]);
        x0.v = p[0]; x1.v = p[1];
#pragma unroll
        for (int q = 0; q < 4; ++q) {
            zA[0][q]   = __hfma2(ca.h[0], x0.h[q], zA[0][q]);
            zA[1][q]   = __hfma2(ca.h[1], x0.h[q], zA[1][q]);
            zA[2][q]   = __hfma2(ca.h[2], x0.h[q], zA[2][q]);
            zA[3][q]   = __hfma2(ca.h[3], x0.h[q], zA[3][q]);
            zA[0][q+4] = __hfma2(ca.h[0], x1.h[q], zA[0][q+4]);
            zA[1][q+4] = __hfma2(ca.h[1], x1.h[q], zA[1][q+4]);
            zA[2][q+4] = __hfma2(ca.h[2], x1.h[q], zA[2][q+4]);
            zA[3][q+4] = __hfma2(ca.h[3], x1.h[q], zA[3][q+4]);
        }
    }
#pragma unroll 2
    for (int e = 26; e < 92; ++e) {
        I4H ca, x0, x1;
        ca.v = aA[e];
        const int4* p = (const int4*)((const char*)ldsh + baseb + ed[e]);
        x0.v = p[0]; x1.v = p[1];
#pragma unroll
        for (int q = 0; q < 4; ++q) {
            zA[2][q]   = __hfma2(ca.h[2], x0.h[q], zA[2][q]);
            zA[3][q]   = __hfma2(ca.h[3], x0.h[q], zA[3][q]);
            zA[2][q+4] = __hfma2(ca.h[2], x1.h[q], zA[2][q+4]);
            zA[3][q+4] = __hfma2(ca.h[3], x1.h[q], zA[3][q+4]);
        }
    }
}

// two REAL harmonics A,B (m=0).  z rows: [0]=A_j0, [1]=A_j1, [2]=B_j0, [3]=B_j1
__device__ __forceinline__ void conv2r(const __half* __restrict__ ldsh, int baseb,
    const int4* __restrict__ aA, const int4* __restrict__ aB,
    const int* __restrict__ ed, h2 (&z)[4][8])
{
#pragma unroll
    for (int r = 0; r < 4; ++r)
#pragma unroll
        for (int q = 0; q < 8; ++q) z[r][q] = __float2half2_rn(0.f);

#pragma unroll 2
    for (int e = 0; e < 6; ++e) {           // j0 only
        I4H ca, cb_, x0, x1;
        ca.v = aA[e]; cb_.v = aB[e];
        const int4* p = (const int4*)((const char*)ldsh + baseb + ed[e]);
        x0.v = p[0]; x1.v = p[1];
#pragma unroll
        for (int q = 0; q < 4; ++q) {
            z[0][q]   = __hfma2(ca.h[0],  x0.h[q], z[0][q]);
            z[2][q]   = __hfma2(cb_.h[0], x0.h[q], z[2][q]);
            z[0][q+4] = __hfma2(ca.h[0],  x1.h[q], z[0][q+4]);
            z[2][q+4] = __hfma2(cb_.h[0], x1.h[q], z[2][q+4]);
        }
    }
#pragma unroll 2
    for (int e = 6; e < 26; ++e) {          // both j
        I4H ca, cb_, x0, x1;
        ca.v = aA[e]; cb_.v = aB[e];
        const int4* p = (const int4*)((const char*)ldsh + baseb + ed[e]);
        x0.v = p[0]; x1.v = p[1];
#pragma unroll
        for (int q = 0; q < 4; ++q) {
            z[0][q]   = __hfma2(ca.h[0],  x0.h[q], z[0][q]);
            z[1][q]   = __hfma2(ca.h[2],  x0.h[q], z[1][q]);
            z[2][q]   = __hfma2(cb_.h[0], x0.h[q], z[2][q]);
            z[3][q]   = __hfma2(cb_.h[2], x0.h[q], z[3][q]);
            z[0][q+4] = __hfma2(ca.h[0],  x1.h[q], z[0][q+4]);
            z[1][q+4] = __hfma2(ca.h[2],  x1.h[q], z[1][q+4]);
            z[2][q+4] = __hfma2(cb_.h[0], x1.h[q], z[2][q+4]);
            z[3][q+4] = __hfma2(cb_.h[2], x1.h[q], z[3][q+4]);
        }
    }
#pragma unroll 2
    for (int e = 26; e < 92; ++e) {         // j1 only
        I4H ca, cb_, x0, x1;
        ca.v = aA[e]; cb_.v = aB[e];
        const int4* p = (const int4*)((const char*)ldsh + baseb + ed[e]);
        x0.v = p[0]; x1.v = p[1];
#pragma unroll
        for (int q = 0; q < 4; ++q) {
            z[1][q]   = __hfma2(ca.h[2],  x0.h[q], z[1][q]);
            z[3][q]   = __hfma2(cb_.h[2], x0.h[q], z[3][q]);
            z[1][q+4] = __hfma2(ca.h[2],  x1.h[q], z[1][q+4]);
            z[3][q+4] = __hfma2(cb_.h[2], x1.h[q], z[3][q+4]);
        }
    }
}

// ---------------- mixing + spectrum + fused projection --------------------

#define CDEL (2*(LYY*LXX) + 2*LXX + 2)

// complex harmonic (m>0): weight 2/(2n+1)
template<int N>
__device__ __forceinline__ void mixc(const h2 (&z)[4][8],
    const int4* __restrict__ wt2n, const float* __restrict__ pwT, float2 (&outa)[16])
{
    const float W = 2.f / (float)(2*N + 1);
#pragma unroll 2
    for (int f = 0; f < 32; ++f) {
        I4H w00, w01, w10, w11;
        w00.v = wt2n[f*4+0]; w01.v = wt2n[f*4+1];
        w10.v = wt2n[f*4+2]; w11.v = wt2n[f*4+3];
        h2 yr = __float2half2_rn(0.f), yi = __float2half2_rn(0.f);
#pragma unroll
        for (int q = 0; q < 4; ++q) {
            yr = __hfma2(w00.h[q], z[0][q],   yr);
            yr = __hfma2(w01.h[q], z[0][q+4], yr);
            yr = __hfma2(w10.h[q], z[2][q],   yr);
            yr = __hfma2(w11.h[q], z[2][q+4], yr);
            yi = __hfma2(w00.h[q], z[1][q],   yi);
            yi = __hfma2(w01.h[q], z[1][q+4], yi);
            yi = __hfma2(w10.h[q], z[3][q],   yi);
            yi = __hfma2(w11.h[q], z[3][q+4], yi);
        }
        float yrf = __low2float(yr) + __high2float(yr);
        float yif = __low2float(yi) + __high2float(yi);
        float s = (yrf*yrf + yif*yif) * W;
        const float2* pw2 = (const float2*)(pwT + (f*4 + N)*32);
#pragma unroll
        for (int k = 0; k < 16; ++k) {
            float2 t = pw2[k];
            outa[k].x = fmaf(t.x, s, outa[k].x);
            outa[k].y = fmaf(t.y, s, outa[k].y);
        }
    }
}

// real harmonic (m=0): weight 1/(2n+1); rows R (j0) and R+1 (j1)
template<int R, int N, bool CENTRAL>
__device__ __forceinline__ void mixr(const h2 (&z)[4][8],
    const int4* __restrict__ wt2n, const int4* __restrict__ cw2,
    const float* __restrict__ cbp, const __half* __restrict__ ldsh, int baseb,
    const float* __restrict__ pwT, float2 (&outa)[16])
{
    const float W = 1.f / (float)(2*N + 1);
    h2 xc[8];
    if (CENTRAL) {
        const int4* pc = (const int4*)((const char*)ldsh + baseb + CDEL*POSB);
        I4H xc0, xc1; xc0.v = pc[0]; xc1.v = pc[1];
#pragma unroll
        for (int q = 0; q < 4; ++q) { xc[q] = xc0.h[q]; xc[q+4] = xc1.h[q]; }
    }
#pragma unroll 2
    for (int f = 0; f < 32; ++f) {
        I4H w00, w01, w10, w11;
        w00.v = wt2n[f*4+0]; w01.v = wt2n[f*4+1];
        w10.v = wt2n[f*4+2]; w11.v = wt2n[f*4+3];
        h2 yr = __float2half2_rn(0.f);
#pragma unroll
        for (int q = 0; q < 4; ++q) {
            yr = __hfma2(w00.h[q], z[R][q],     yr);
            yr = __hfma2(w01.h[q], z[R][q+4],   yr);
            yr = __hfma2(w10.h[q], z[R+1][q],   yr);
            yr = __hfma2(w11.h[q], z[R+1][q+4], yr);
        }
        float yrf = __low2float(yr) + __high2float(yr);
        if (CENTRAL) {
            I4H c0, c1; c0.v = cw2[f*2]; c1.v = cw2[f*2+1];
            h2 acc = __float2half2_rn(0.f);
#pragma unroll
            for (int q = 0; q < 4; ++q) {
                acc = __hfma2(c0.h[q], xc[q],   acc);
                acc = __hfma2(c1.h[q], xc[q+4], acc);
            }
            yrf += cbp[f] + __low2float(acc) + __high2float(acc);
        }
        float s = yrf*yrf * W;
        const float2* pw2 = (const float2*)(pwT + (f*4 + N)*32);
#pragma unroll
        for (int k = 0; k < 16; ++k) {
            float2 t = pw2[k];
            outa[k].x = fmaf(t.x, s, outa[k].x);
            outa[k].y = fmaf(t.y, s, outa[k].y);
        }
    }
}

__global__ __launch_bounds__(256, 2) void ssh_main(
    const float* __restrict__ x, const float* __restrict__ cb,
    const char* __restrict__ wsb, float* __restrict__ out)
{
    __shared__ __align__(16) char lds[LDS_SZ];
    __half* ldsh = (__half*)(lds + XT_B);
    const int tid = threadIdx.x;
    const int x0 = blockIdx.x * TX, y0 = blockIdx.y * TY, z0 = blockIdx.z * TZ;

    // stage x -> f16 LDS, channel-fastest, 2 channels per write (b32)
    for (int i = tid; i < NPOS * 8; i += 256) {
        int cp = i / NPOS;
        int pos = i - cp * NPOS;
        int lx = pos % LXX; int t1 = pos / LXX;
        int ly = t1 % LYY;  int lz = t1 / LYY;
        int gx = x0 + lx - 2, gy = y0 + ly - 2, gz = z0 + lz - 2;
        h2 hv = __float2half2_rn(0.f);
        if ((unsigned)gx < 48u && (unsigned)gy < 48u && (unsigned)gz < 48u) {
            int gi = ((2*cp*48 + gz)*48 + gy)*48 + gx;
            hv = __floats2half2_rn(x[gi], x[gi + 48*48*48]);
        }
        *(h2*)(ldsh + pos*CPAD + 2*cp) = hv;
    }
    // stage coef tables -> LDS (uniform-broadcast consumers)
    {
        const int4* gat = (const int4*)(wsb + ATAB2_B);
        int4* lat = (int4*)(lds + ATL_B);
        for (int i = tid; i < 1472; i += 256) lat[i] = gat[i];
        if (tid < 92) ((int*)(lds + EDL_B))[tid] = ((const int*)(wsb + ED_B))[tid];
    }
    __syncthreads();

    const int hf  = tid >> 7;
    const int vid = tid & 127;
    const int tx = vid & 7, ty = (vid >> 3) & 3, tz = vid >> 5;
    const int baseb = (tz*(LYY*LXX) + ty*LXX + tx) * POSB;

    const int4* __restrict__ atab = (const int4*)(lds + ATL_B);
    const int*  __restrict__ ed   = (const int*)(lds + EDL_B);
    const int4* __restrict__ wt2  = (const int4*)(wsb + WT2_B);
    const int4* __restrict__ cw2  = (const int4*)(wsb + CW2_B);
    const float* __restrict__ pwT = (const float*)(wsb + PWT_B);
    const float* __restrict__ obase = (const float*)(wsb + OB_B);

    float2 outa[16];
#pragma unroll
    for (int k = 0; k < 16; ++k) outa[k] = make_float2(0.f, 0.f);

    h2 zA[4][8], zB[4][8];
    if (hf == 0) {
        // n=3: (3,1)=h13, (3,2)=h14, (3,3)=h15, (3,0)=h12; n=0: (0,0)=h0 + central
        conv2c(ldsh, baseb, atab + 13*92, atab + 14*92, ed, zA, zB);
        mixc<3>(zA, wt2 + 3*128, pwT, outa);
        mixc<3>(zB, wt2 + 3*128, pwT, outa);
        conv1c(ldsh, baseb, atab + 15*92, ed, zA);
        mixc<3>(zA, wt2 + 3*128, pwT, outa);
        conv2r(ldsh, baseb, atab + 12*92, atab + 0*92, ed, zB);
        mixr<0,3,false>(zB, wt2 + 3*128, cw2, cb, ldsh, baseb, pwT, outa);
        mixr<2,0,true >(zB, wt2 + 0*128, cw2, cb, ldsh, baseb, pwT, outa);
    } else {
        // n=2: (2,1)=h7, (2,2)=h8, (2,0)=h6; n=1: (1,1)=h3, (1,0)=h2
        conv2c(ldsh, baseb, atab + 7*92, atab + 8*92, ed, zA, zB);
        mixc<2>(zA, wt2 + 2*128, pwT, outa);
        mixc<2>(zB, wt2 + 2*128, pwT, outa);
        conv2r(ldsh, baseb, atab + 6*92, atab + 2*92, ed, zA);
        mixr<0,2,false>(zA, wt2 + 2*128, cw2, cb, ldsh, baseb, pwT, outa);
        conv1c(ldsh, baseb, atab + 3*92, ed, zB);
        mixc<1>(zB, wt2 + 1*128, pwT, outa);
        mixr<2,1,false>(zA, wt2 + 1*128, cw2, cb, ldsh, baseb, pwT, outa);
    }

    // merge halves through LDS (x-tile is dead now); stride 33 avoids conflicts
    __syncthreads();
    float* lmerge = (float*)lds;
    if (hf == 1) {
#pragma unroll
        for (int k = 0; k < 16; ++k) {
            lmerge[vid*33 + 2*k]     = outa[k].x;
            lmerge[vid*33 + 2*k + 1] = outa[k].y;
        }
    }
    __syncthreads();
    if (hf == 0) {
        const int gz = z0 + tz, gy = y0 + ty, gx = x0 + tx;
#pragma unroll
        for (int k = 0; k < 16; ++k) {
            float v0 = obase[2*k]   + outa[k].x + lmerge[vid*33 + 2*k];
            float v1 = obase[2*k+1] + outa[k].y + lmerge[vid*33 + 2*k + 1];
            out[(((2*k)*48   + gz)*48 + gy)*48 + gx] = fmaxf(v0, 0.f);
            out[(((2*k+1)*48 + gz)*48 + gy)*48 + gx] = fmaxf(v1, 0.f);
        }
    }
}

extern "C" void kernel_launch(void* const* d_in, const int* in_sizes, int n_in,
                              void* d_out, int out_size, void* d_ws, size_t ws_size,
                              hipStream_t stream) {
    const float* x  = (const float*)d_in[0];
    const float* w  = (const float*)d_in[1];
    const float* cw = (const float*)d_in[2];
    const float* cb = (const float*)d_in[3];
    const float* sb = (const float*)d_in[4];
    const float* pw = (const float*)d_in[5];
    const float* pb = (const float*)d_in[6];
    float* out = (float*)d_out;
    char* wsb = (char*)d_ws;

    ssh_init<<<dim3(1), dim3(256), 0, stream>>>(w, cw, pw, sb, pb, wsb);
    ssh_main<<<dim3(48/TX, 48/TY, 48/TZ), dim3(256), 0, stream>>>(x, cb, wsb, out);
}

// Round 8
// 160.291 us; speedup vs baseline: 1.7949x; 1.1905x over previous
//
#include <hip/hip_runtime.h>
#include <hip/hip_fp16.h>
#include <math.h>

// ---------------------------------------------------------------------------
// SSHConv3D fused, round 8: r4 structure (m>=0 symmetry, packed-f16, 36.9 KB
// LDS, 3 blocks/CU) + same-degree spec pairing before projection (10 -> 6
// projection passes per thread) + deeper conv unroll (2 -> 3/4).
// r7 lesson: coef-in-LDS was issue-neutral and cost occupancy -> reverted.
//
// ws layout (bytes):
//   [0,     23552) atab2 : h2[16 h][92 e][4] = {(ar0),(ai0),(ar1),(ai1)} repl. pairs
//   [23552, 31744) wT2   : h2[n][f][j][8 cp]
//   [31744, 32768) cw2   : h2[f][8 cp]
//   [32768, 49152) pwT   : f32[(f*4+n)][fo]
//   [49152, 49280) obase : f32[32]
//   [49280, 49648) edelta: int[92] byte offsets (pre-scaled by 48)
// Entry segments: [0,6)=j0-only, [6,26)=both j, [26,92)=j1-only.
// ---------------------------------------------------------------------------

#define TX 8
#define TY 4
#define TZ 4
#define LXX 12
#define LYY 8
#define LZZ 8
#define NPOS 768
#define CPAD 24
#define POSB 48

#define ATAB2_B 0
#define WT2_B   23552
#define CW2_B   31744
#define PWT_B   32768
#define OB_B    49152
#define ED_B    49280

typedef __half2 h2;
union I4H { int4 v; h2 h[4]; };

__global__ __launch_bounds__(256) void ssh_init(
    const float* __restrict__ w, const float* __restrict__ cw,
    const float* __restrict__ proj_w, const float* __restrict__ spec_bias,
    const float* __restrict__ proj_b, char* __restrict__ wsb)
{
    __shared__ float shr[125][16];
    __shared__ float shi[125][16];
    __shared__ float prof[125][2];
    __shared__ float norms[2][16];
    __shared__ int epos[92];
    const int tid = threadIdx.x;
    const float fourpi = 4.0f * 3.14159265358979323846f;

    for (int p = tid; p < 125; p += 256) {
        int d2 = p % 5, d1 = (p / 5) % 5, d0 = p / 25;
        float xc = (float)(d1 - 2), yc = (float)(d0 - 2), zc = (float)(d2 - 2);
        float r2 = xc*xc + yc*yc + zc*zc;
        float r  = sqrtf(r2);
        float phi = atan2f(yc, xc);
        float ct = (r > 0.f) ? (zc / r) : 0.f;
        float st = sqrtf(fmaxf(0.f, 1.f - ct*ct));
        float c1 = cosf(phi), s1 = sinf(phi);
        float c2 = c1*c1 - s1*s1, s2 = 2.f*s1*c1;
        float c3 = c2*c1 - s2*s1, s3 = s2*c1 + c2*s1;
        float P10 = ct,              P11 = -st;
        float P20 = 0.5f*(3.f*ct*ct - 1.f), P21 = -3.f*ct*st, P22 = 3.f*st*st;
        float P30 = 0.5f*(5.f*ct*ct*ct - 3.f*ct);
        float P31 = -1.5f*(5.f*ct*ct - 1.f)*st;
        float P32 = 15.f*ct*st*st;
        float P33 = -15.f*st*st*st;
        float N00 = sqrtf(1.f/fourpi);
        float N10 = sqrtf(3.f/fourpi);
        float N11 = sqrtf(3.f/fourpi * 0.5f);
        float N20 = sqrtf(5.f/fourpi);
        float N21 = sqrtf(5.f/fourpi / 6.f);
        float N22 = sqrtf(5.f/fourpi / 24.f);
        float N30 = sqrtf(7.f/fourpi);
        float N31 = sqrtf(7.f/fourpi / 12.f);
        float N32 = sqrtf(7.f/fourpi / 120.f);
        float N33 = sqrtf(7.f/fourpi / 720.f);
        float b;
        shr[p][0] = N00;               shi[p][0] = 0.f;
        shr[p][2] = N10*P10;           shi[p][2] = 0.f;
        b = N11*P11;
        shr[p][3] =  b*c1;             shi[p][3] =  b*s1;
        shr[p][1] = -b*c1;             shi[p][1] =  b*s1;
        shr[p][6] = N20*P20;           shi[p][6] = 0.f;
        b = N21*P21;
        shr[p][7] =  b*c1;             shi[p][7] =  b*s1;
        shr[p][5] = -b*c1;             shi[p][5] =  b*s1;
        b = N22*P22;
        shr[p][8] =  b*c2;             shi[p][8] =  b*s2;
        shr[p][4] =  b*c2;             shi[p][4] = -b*s2;
        shr[p][12] = N30*P30;          shi[p][12] = 0.f;
        b = N31*P31;
        shr[p][13] =  b*c1;            shi[p][13] =  b*s1;
        shr[p][11] = -b*c1;            shi[p][11] =  b*s1;
        b = N32*P32;
        shr[p][14] =  b*c2;            shi[p][14] =  b*s2;
        shr[p][10] =  b*c2;            shi[p][10] = -b*s2;
        b = N33*P33;
        shr[p][15] =  b*c3;            shi[p][15] =  b*s3;
        shr[p][9]  = -b*c3;            shi[p][9]  =  b*s3;
        prof[p][0] = fmaxf(0.f, 1.f - fabsf(r - 1.f));
        prof[p][1] = fmaxf(0.f, 1.f - fabsf(r - 2.f));
    }
    __syncthreads();

    if (tid < 32) {
        int j = tid >> 4, h = tid & 15;
        float acc = 0.f;
        for (int p = 0; p < 125; ++p) {
            float pr = prof[p][j];
            acc += pr*pr*(shr[p][h]*shr[p][h] + shi[p][h]*shi[p][h]);
        }
        float nn = sqrtf(acc);
        norms[j][h] = (nn > 0.f) ? nn : 1.f;
    }
    // entry ordering via rank (cls0 base 0, cls1 base 6, cls2 base 26)
    if (tid < 125) {
        int p = tid;
        int d2 = p % 5, d1 = (p / 5) % 5, d0 = p / 25;
        int ix = d1 - 2, iy = d0 - 2, iz = d2 - 2;
        int r2i = ix*ix + iy*iy + iz*iz;
        int cls = (r2i == 1) ? 0 : (r2i == 2 || r2i == 3) ? 1
                : (r2i == 4 || r2i == 5 || r2i == 6 || r2i == 8) ? 2 : -1;
        if (cls >= 0) {
            int rank = (cls == 0) ? 0 : (cls == 1) ? 6 : 26;
            for (int q = 0; q < p; ++q) {
                int e2 = q % 5, e1 = (q / 5) % 5, e0 = q / 25;
                int jx = e1 - 2, jy = e0 - 2, jz = e2 - 2;
                int s2i = jx*jx + jy*jy + jz*jz;
                int c2i = (s2i == 1) ? 0 : (s2i == 2 || s2i == 3) ? 1
                       : (s2i == 4 || s2i == 5 || s2i == 6 || s2i == 8) ? 2 : -1;
                rank += (c2i == cls) ? 1 : 0;
            }
            epos[rank] = p;
            ((int*)(wsb + ED_B))[rank] = (d0*(LYY*LXX) + d1*LXX + d2) * POSB;
        }
    }
    __syncthreads();

    h2* at2 = (h2*)(wsb + ATAB2_B);
    for (int t = tid; t < 92*16; t += 256) {
        int e = t >> 4, h = t & 15;
        int p = epos[e];
        float c0 = prof[p][0] / norms[0][h];
        float c1v = prof[p][1] / norms[1][h];
        at2[(h*92+e)*4 + 0] = __float2half2_rn(c0*shr[p][h]);
        at2[(h*92+e)*4 + 1] = __float2half2_rn(c0*shi[p][h]);
        at2[(h*92+e)*4 + 2] = __float2half2_rn(c1v*shr[p][h]);
        at2[(h*92+e)*4 + 3] = __float2half2_rn(c1v*shi[p][h]);
    }
    // wT2: h2 index = n*512 + f*16 + j*8 + cp
    h2* wt2h = (h2*)(wsb + WT2_B);
    for (int t = tid; t < 2048; t += 256) {
        int n = t >> 9, f = (t >> 4) & 31, j = (t >> 3) & 1, cp = t & 7;
        float a = w[((2*cp*32 + f)*2 + j)*4 + n];
        float b = w[(((2*cp+1)*32 + f)*2 + j)*4 + n];
        wt2h[t] = __halves2half2(__float2half(a), __float2half(b));
    }
    // cw2: h2 index = f*8 + cp
    h2* cw2h = (h2*)(wsb + CW2_B);
    for (int t = tid; t < 256; t += 256) {
        int f = t >> 3, cp = t & 7;
        cw2h[t] = __halves2half2(__float2half(cw[f*16 + 2*cp]),
                                 __float2half(cw[f*16 + 2*cp + 1]));
    }
    // pwT f32 [(f*4+n)][fo]
    float* pwT = (float*)(wsb + PWT_B);
    for (int t = tid; t < 4096; t += 256) {
        int i = t >> 5, fo = t & 31;
        pwT[t] = proj_w[fo*128 + i];
    }
    if (tid < 32) {
        float acc = proj_b[tid];
        for (int i = 0; i < 128; ++i) acc += proj_w[tid*128 + i] * spec_bias[i];
        ((float*)(wsb + OB_B))[tid] = acc;
    }
}

// ---------------- conv passes --------------------------------------------
// complex z rows: [0]=r_j0, [1]=i_j0, [2]=r_j1, [3]=i_j1

__device__ __forceinline__ void conv2c(const __half* __restrict__ ldsh, int baseb,
    const int4* __restrict__ aA, const int4* __restrict__ aB,
    const int* __restrict__ ed, h2 (&zA)[4][8], h2 (&zB)[4][8])
{
#pragma unroll
    for (int r = 0; r < 4; ++r)
#pragma unroll
        for (int q = 0; q < 8; ++q) { zA[r][q] = __float2half2_rn(0.f); zB[r][q] = __float2half2_rn(0.f); }

#pragma unroll 3
    for (int e = 0; e < 6; ++e) {           // j0 only
        I4H ca, cb_, x0, x1;
        ca.v = aA[e]; cb_.v = aB[e];
        const int4* p = (const int4*)((const char*)ldsh + baseb + ed[e]);
        x0.v = p[0]; x1.v = p[1];
#pragma unroll
        for (int q = 0; q < 4; ++q) {
            zA[0][q]   = __hfma2(ca.h[0],  x0.h[q], zA[0][q]);
            zA[1][q]   = __hfma2(ca.h[1],  x0.h[q], zA[1][q]);
            zB[0][q]   = __hfma2(cb_.h[0], x0.h[q], zB[0][q]);
            zB[1][q]   = __hfma2(cb_.h[1], x0.h[q], zB[1][q]);
            zA[0][q+4] = __hfma2(ca.h[0],  x1.h[q], zA[0][q+4]);
            zA[1][q+4] = __hfma2(ca.h[1],  x1.h[q], zA[1][q+4]);
            zB[0][q+4] = __hfma2(cb_.h[0], x1.h[q], zB[0][q+4]);
            zB[1][q+4] = __hfma2(cb_.h[1], x1.h[q], zB[1][q+4]);
        }
    }
#pragma unroll 4
    for (int e = 6; e < 26; ++e) {          // both j
        I4H ca, cb_, x0, x1;
        ca.v = aA[e]; cb_.v = aB[e];
        const int4* p = (const int4*)((const char*)ldsh + baseb + ed[e]);
        x0.v = p[0]; x1.v = p[1];
#pragma unroll
        for (int q = 0; q < 4; ++q) {
            zA[0][q]   = __hfma2(ca.h[0],  x0.h[q], zA[0][q]);
            zA[1][q]   = __hfma2(ca.h[1],  x0.h[q], zA[1][q]);
            zA[2][q]   = __hfma2(ca.h[2],  x0.h[q], zA[2][q]);
            zA[3][q]   = __hfma2(ca.h[3],  x0.h[q], zA[3][q]);
            zB[0][q]   = __hfma2(cb_.h[0], x0.h[q], zB[0][q]);
            zB[1][q]   = __hfma2(cb_.h[1], x0.h[q], zB[1][q]);
            zB[2][q]   = __hfma2(cb_.h[2], x0.h[q], zB[2][q]);
            zB[3][q]   = __hfma2(cb_.h[3], x0.h[q], zB[3][q]);
            zA[0][q+4] = __hfma2(ca.h[0],  x1.h[q], zA[0][q+4]);
            zA[1][q+4] = __hfma2(ca.h[1],  x1.h[q], zA[1][q+4]);
            zA[2][q+4] = __hfma2(ca.h[2],  x1.h[q], zA[2][q+4]);
            zA[3][q+4] = __hfma2(ca.h[3],  x1.h[q], zA[3][q+4]);
            zB[0][q+4] = __hfma2(cb_.h[0], x1.h[q], zB[0][q+4]);
            zB[1][q+4] = __hfma2(cb_.h[1], x1.h[q], zB[1][q+4]);
            zB[2][q+4] = __hfma2(cb_.h[2], x1.h[q], zB[2][q+4]);
            zB[3][q+4] = __hfma2(cb_.h[3], x1.h[q], zB[3][q+4]);
        }
    }
#pragma unroll 3
    for (int e = 26; e < 92; ++e) {         // j1 only
        I4H ca, cb_, x0, x1;
        ca.v = aA[e]; cb_.v = aB[e];
        const int4* p = (const int4*)((const char*)ldsh + baseb + ed[e]);
        x0.v = p[0]; x1.v = p[1];
#pragma unroll
        for (int q = 0; q < 4; ++q) {
            zA[2][q]   = __hfma2(ca.h[2],  x0.h[q], zA[2][q]);
            zA[3][q]   = __hfma2(ca.h[3],  x0.h[q], zA[3][q]);
            zB[2][q]   = __hfma2(cb_.h[2], x0.h[q], zB[2][q]);
            zB[3][q]   = __hfma2(cb_.h[3], x0.h[q], zB[3][q]);
            zA[2][q+4] = __hfma2(ca.h[2],  x1.h[q], zA[2][q+4]);
            zA[3][q+4] = __hfma2(ca.h[3],  x1.h[q], zA[3][q+4]);
            zB[2][q+4] = __hfma2(cb_.h[2], x1.h[q], zB[2][q+4]);
            zB[3][q+4] = __hfma2(cb_.h[3], x1.h[q], zB[3][q+4]);
        }
    }
}

__device__ __forceinline__ void conv1c(const __half* __restrict__ ldsh, int baseb,
    const int4* __restrict__ aA, const int* __restrict__ ed, h2 (&zA)[4][8])
{
#pragma unroll
    for (int r = 0; r < 4; ++r)
#pragma unroll
        for (int q = 0; q < 8; ++q) zA[r][q] = __float2half2_rn(0.f);

#pragma unroll 3
    for (int e = 0; e < 6; ++e) {
        I4H ca, x0, x1;
        ca.v = aA[e];
        const int4* p = (const int4*)((const char*)ldsh + baseb + ed[e]);
        x0.v = p[0]; x1.v = p[1];
#pragma unroll
        for (int q = 0; q < 4; ++q) {
            zA[0][q]   = __hfma2(ca.h[0], x0.h[q], zA[0][q]);
            zA[1][q]   = __hfma2(ca.h[1], x0.h[q], zA[1][q]);
            zA[0][q+4] = __hfma2(ca.h[0], x1.h[q], zA[0][q+4]);
            zA[1][q+4] = __hfma2(ca.h[1], x1.h[q], zA[1][q+4]);
        }
    }
#pragma unroll 4
    for (int e = 6; e < 26; ++e) {
        I4H ca, x0, x1;
        ca.v = aA[e];
        const int4* p = (const int4*)((const char*)ldsh + baseb + ed[e]);
        x0.v = p[0]; x1.v = p[1];
#pragma unroll
        for (int q = 0; q < 4; ++q) {
            zA[0][q]   = __hfma2(ca.h[0], x0.h[q], zA[0][q]);
            zA[1][q]   = __hfma2(ca.h[1], x0.h[q], zA[1][q]);
            zA[2][q]   = __hfma2(ca.h[2], x0.h[q], zA[2][q]);
            zA[3][q]   = __hfma2(ca.h[3], x0.h[q], zA[3][q]);
            zA[0][q+4] = __hfma2(ca.h[0], x1.h[q], zA[0][q+4]);
            zA[1][q+4] = __hfma2(ca.h[1], x1.h[q], zA[1][q+4]);
            zA[2][q+4] = __hfma2(ca.h[2], x1.h[q], zA[2][q+4]);
            zA[3][q+4] = __hfma2(ca.h[3], x1.h[q], zA[3][q+4]);
        }
    }
#pragma unroll 3
    for (int e = 26; e < 92; ++e) {
        I4H ca, x0, x1;
        ca.v = aA[e];
        const int4* p = (const int4*)((const char*)ldsh + baseb + ed[e]);
        x0.v = p[0]; x1.v = p[1];
#pragma unroll
        for (int q = 0; q < 4; ++q) {
            zA[2][q]   = __hfma2(ca.h[2], x0.h[q], zA[2][q]);
            zA[3][q]   = __hfma2(ca.h[3], x0.h[q], zA[3][q]);
            zA[2][q+4] = __hfma2(ca.h[2], x1.h[q], zA[2][q+4]);
            zA[3][q+4] = __hfma2(ca.h[3], x1.h[q], zA[3][q+4]);
        }
    }
}

// two REAL harmonics A,B (m=0).  z rows: [0]=A_j0, [1]=A_j1, [2]=B_j0, [3]=B_j1
__device__ __forceinline__ void conv2r(const __half* __restrict__ ldsh, int baseb,
    const int4* __restrict__ aA, const int4* __restrict__ aB,
    const int* __restrict__ ed, h2 (&z)[4][8])
{
#pragma unroll
    for (int r = 0; r < 4; ++r)
#pragma unroll
        for (int q = 0; q < 8; ++q) z[r][q] = __float2half2_rn(0.f);

#pragma unroll 3
    for (int e = 0; e < 6; ++e) {           // j0 only
        I4H ca, cb_, x0, x1;
        ca.v = aA[e]; cb_.v = aB[e];
        const int4* p = (const int4*)((const char*)ldsh + baseb + ed[e]);
        x0.v = p[0]; x1.v = p[1];
#pragma unroll
        for (int q = 0; q < 4; ++q) {
            z[0][q]   = __hfma2(ca.h[0],  x0.h[q], z[0][q]);
            z[2][q]   = __hfma2(cb_.h[0], x0.h[q], z[2][q]);
            z[0][q+4] = __hfma2(ca.h[0],  x1.h[q], z[0][q+4]);
            z[2][q+4] = __hfma2(cb_.h[0], x1.h[q], z[2][q+4]);
        }
    }
#pragma unroll 4
    for (int e = 6; e < 26; ++e) {          // both j
        I4H ca, cb_, x0, x1;
        ca.v = aA[e]; cb_.v = aB[e];
        const int4* p = (const int4*)((const char*)ldsh + baseb + ed[e]);
        x0.v = p[0]; x1.v = p[1];
#pragma unroll
        for (int q = 0; q < 4; ++q) {
            z[0][q]   = __hfma2(ca.h[0],  x0.h[q], z[0][q]);
            z[1][q]   = __hfma2(ca.h[2],  x0.h[q], z[1][q]);
            z[2][q]   = __hfma2(cb_.h[0], x0.h[q], z[2][q]);
            z[3][q]   = __hfma2(cb_.h[2], x0.h[q], z[3][q]);
            z[0][q+4] = __hfma2(ca.h[0],  x1.h[q], z[0][q+4]);
            z[1][q+4] = __hfma2(ca.h[2],  x1.h[q], z[1][q+4]);
            z[2][q+4] = __hfma2(cb_.h[0], x1.h[q], z[2][q+4]);
            z[3][q+4] = __hfma2(cb_.h[2], x1.h[q], z[3][q+4]);
        }
    }
#pragma unroll 3
    for (int e = 26; e < 92; ++e) {         // j1 only
        I4H ca, cb_, x0, x1;
        ca.v = aA[e]; cb_.v = aB[e];
        const int4* p = (const int4*)((const char*)ldsh + baseb + ed[e]);
        x0.v = p[0]; x1.v = p[1];
#pragma unroll
        for (int q = 0; q < 4; ++q) {
            z[1][q]   = __hfma2(ca.h[2],  x0.h[q], z[1][q]);
            z[3][q]   = __hfma2(cb_.h[2], x0.h[q], z[3][q]);
            z[1][q+4] = __hfma2(ca.h[2],  x1.h[q], z[1][q+4]);
            z[3][q+4] = __hfma2(cb_.h[2], x1.h[q], z[3][q+4]);
        }
    }
}

// ---------------- mixing + spectrum + fused projection --------------------

#define CDEL (2*(LYY*LXX) + 2*LXX + 2)

// two complex harmonics of the SAME degree N: one projection pass
template<int N>
__device__ __forceinline__ void mixc2(const h2 (&zA)[4][8], const h2 (&zB)[4][8],
    const int4* __restrict__ wt2n, const float* __restrict__ pwT, float2 (&outa)[16])
{
    const float W = 2.f / (float)(2*N + 1);
#pragma unroll 2
    for (int f = 0; f < 32; ++f) {
        I4H w00, w01, w10, w11;
        w00.v = wt2n[f*4+0]; w01.v = wt2n[f*4+1];
        w10.v = wt2n[f*4+2]; w11.v = wt2n[f*4+3];
        h2 yrA = __float2half2_rn(0.f), yiA = __float2half2_rn(0.f);
        h2 yrB = __float2half2_rn(0.f), yiB = __float2half2_rn(0.f);
#pragma unroll
        for (int q = 0; q < 4; ++q) {
            yrA = __hfma2(w00.h[q], zA[0][q],   yrA);
            yrA = __hfma2(w01.h[q], zA[0][q+4], yrA);
            yrA = __hfma2(w10.h[q], zA[2][q],   yrA);
            yrA = __hfma2(w11.h[q], zA[2][q+4], yrA);
            yiA = __hfma2(w00.h[q], zA[1][q],   yiA);
            yiA = __hfma2(w01.h[q], zA[1][q+4], yiA);
            yiA = __hfma2(w10.h[q], zA[3][q],   yiA);
            yiA = __hfma2(w11.h[q], zA[3][q+4], yiA);
            yrB = __hfma2(w00.h[q], zB[0][q],   yrB);
            yrB = __hfma2(w01.h[q], zB[0][q+4], yrB);
            yrB = __hfma2(w10.h[q], zB[2][q],   yrB);
            yrB = __hfma2(w11.h[q], zB[2][q+4], yrB);
            yiB = __hfma2(w00.h[q], zB[1][q],   yiB);
            yiB = __hfma2(w01.h[q], zB[1][q+4], yiB);
            yiB = __hfma2(w10.h[q], zB[3][q],   yiB);
            yiB = __hfma2(w11.h[q], zB[3][q+4], yiB);
        }
        float ra = __low2float(yrA) + __high2float(yrA);
        float ia = __low2float(yiA) + __high2float(yiA);
        float rb = __low2float(yrB) + __high2float(yrB);
        float ib = __low2float(yiB) + __high2float(yiB);
        float s = (ra*ra + ia*ia + rb*rb + ib*ib) * W;
        const float2* pw2 = (const float2*)(pwT + (f*4 + N)*32);
#pragma unroll
        for (int k = 0; k < 16; ++k) {
            float2 t = pw2[k];
            outa[k].x = fmaf(t.x, s, outa[k].x);
            outa[k].y = fmaf(t.y, s, outa[k].y);
        }
    }
}

// one complex harmonic (zC) + one real harmonic (zR rows RR,RR+1), same degree N
template<int RR, int N>
__device__ __forceinline__ void mix_cr(const h2 (&zC)[4][8], const h2 (&zR)[4][8],
    const int4* __restrict__ wt2n, const float* __restrict__ pwT, float2 (&outa)[16])
{
    const float Wc = 2.f / (float)(2*N + 1);
    const float Wr = 1.f / (float)(2*N + 1);
#pragma unroll 2
    for (int f = 0; f < 32; ++f) {
        I4H w00, w01, w10, w11;
        w00.v = wt2n[f*4+0]; w01.v = wt2n[f*4+1];
        w10.v = wt2n[f*4+2]; w11.v = wt2n[f*4+3];
        h2 yr = __float2half2_rn(0.f), yi = __float2half2_rn(0.f);
        h2 yR = __float2half2_rn(0.f);
#pragma unroll
        for (int q = 0; q < 4; ++q) {
            yr = __hfma2(w00.h[q], zC[0][q],   yr);
            yr = __hfma2(w01.h[q], zC[0][q+4], yr);
            yr = __hfma2(w10.h[q], zC[2][q],   yr);
            yr = __hfma2(w11.h[q], zC[2][q+4], yr);
            yi = __hfma2(w00.h[q], zC[1][q],   yi);
            yi = __hfma2(w01.h[q], zC[1][q+4], yi);
            yi = __hfma2(w10.h[q], zC[3][q],   yi);
            yi = __hfma2(w11.h[q], zC[3][q+4], yi);
            yR = __hfma2(w00.h[q], zR[RR][q],     yR);
            yR = __hfma2(w01.h[q], zR[RR][q+4],   yR);
            yR = __hfma2(w10.h[q], zR[RR+1][q],   yR);
            yR = __hfma2(w11.h[q], zR[RR+1][q+4], yR);
        }
        float rc = __low2float(yr) + __high2float(yr);
        float ic = __low2float(yi) + __high2float(yi);
        float rr = __low2float(yR) + __high2float(yR);
        float s = (rc*rc + ic*ic) * Wc + rr*rr * Wr;
        const float2* pw2 = (const float2*)(pwT + (f*4 + N)*32);
#pragma unroll
        for (int k = 0; k < 16; ++k) {
            float2 t = pw2[k];
            outa[k].x = fmaf(t.x, s, outa[k].x);
            outa[k].y = fmaf(t.y, s, outa[k].y);
        }
    }
}

// single real harmonic (m=0), rows R,R+1; optional central conv fold (h0)
template<int R, int N, bool CENTRAL>
__device__ __forceinline__ void mixr(const h2 (&z)[4][8],
    const int4* __restrict__ wt2n, const int4* __restrict__ cw2,
    const float* __restrict__ cbp, const __half* __restrict__ ldsh, int baseb,
    const float* __restrict__ pwT, float2 (&outa)[16])
{
    const float W = 1.f / (float)(2*N + 1);
    h2 xc[8];
    if (CENTRAL) {
        const int4* pc = (const int4*)((const char*)ldsh + baseb + CDEL*POSB);
        I4H xc0, xc1; xc0.v = pc[0]; xc1.v = pc[1];
#pragma unroll
        for (int q = 0; q < 4; ++q) { xc[q] = xc0.h[q]; xc[q+4] = xc1.h[q]; }
    }
#pragma unroll 2
    for (int f = 0; f < 32; ++f) {
        I4H w00, w01, w10, w11;
        w00.v = wt2n[f*4+0]; w01.v = wt2n[f*4+1];
        w10.v = wt2n[f*4+2]; w11.v = wt2n[f*4+3];
        h2 yr = __float2half2_rn(0.f);
#pragma unroll
        for (int q = 0; q < 4; ++q) {
            yr = __hfma2(w00.h[q], z[R][q],     yr);
            yr = __hfma2(w01.h[q], z[R][q+4],   yr);
            yr = __hfma2(w10.h[q], z[R+1][q],   yr);
            yr = __hfma2(w11.h[q], z[R+1][q+4], yr);
        }
        float yrf = __low2float(yr) + __high2float(yr);
        if (CENTRAL) {
            I4H c0, c1; c0.v = cw2[f*2]; c1.v = cw2[f*2+1];
            h2 acc = __float2half2_rn(0.f);
#pragma unroll
            for (int q = 0; q < 4; ++q) {
                acc = __hfma2(c0.h[q], xc[q],   acc);
                acc = __hfma2(c1.h[q], xc[q+4], acc);
            }
            yrf += cbp[f] + __low2float(acc) + __high2float(acc);
        }
        float s = yrf*yrf * W;
        const float2* pw2 = (const float2*)(pwT + (f*4 + N)*32);
#pragma unroll
        for (int k = 0; k < 16; ++k) {
            float2 t = pw2[k];
            outa[k].x = fmaf(t.x, s, outa[k].x);
            outa[k].y = fmaf(t.y, s, outa[k].y);
        }
    }
}

__global__ __launch_bounds__(256, 3) void ssh_main(
    const float* __restrict__ x, const float* __restrict__ cb,
    const char* __restrict__ wsb, float* __restrict__ out)
{
    __shared__ __align__(16) __half ldsh[NPOS * CPAD];   // 36864 B
    const int tid = threadIdx.x;
    const int x0 = blockIdx.x * TX, y0 = blockIdx.y * TY, z0 = blockIdx.z * TZ;

    // stage x -> f16 LDS, channel-fastest, 2 channels per write (b32)
    for (int i = tid; i < NPOS * 8; i += 256) {
        int cp = i / NPOS;
        int pos = i - cp * NPOS;
        int lx = pos % LXX; int t1 = pos / LXX;
        int ly = t1 % LYY;  int lz = t1 / LYY;
        int gx = x0 + lx - 2, gy = y0 + ly - 2, gz = z0 + lz - 2;
        h2 hv = __float2half2_rn(0.f);
        if ((unsigned)gx < 48u && (unsigned)gy < 48u && (unsigned)gz < 48u) {
            int gi = ((2*cp*48 + gz)*48 + gy)*48 + gx;
            hv = __floats2half2_rn(x[gi], x[gi + 48*48*48]);
        }
        *(h2*)(ldsh + pos*CPAD + 2*cp) = hv;
    }
    __syncthreads();

    const int hf  = tid >> 7;
    const int vid = tid & 127;
    const int tx = vid & 7, ty = (vid >> 3) & 3, tz = vid >> 5;
    const int baseb = (tz*(LYY*LXX) + ty*LXX + tx) * POSB;

    const int4* __restrict__ atab = (const int4*)(wsb + ATAB2_B);
    const int*  __restrict__ ed   = (const int*)(wsb + ED_B);
    const int4* __restrict__ wt2  = (const int4*)(wsb + WT2_B);
    const int4* __restrict__ cw2  = (const int4*)(wsb + CW2_B);
    const float* __restrict__ pwT = (const float*)(wsb + PWT_B);
    const float* __restrict__ obase = (const float*)(wsb + OB_B);

    float2 outa[16];
#pragma unroll
    for (int k = 0; k < 16; ++k) outa[k] = make_float2(0.f, 0.f);

    h2 zA[4][8], zB[4][8];
    if (hf == 0) {
        // n=3: h13,h14 (complex pair), h15 (complex) + h12 (real); n=0: h0 + central
        conv2c(ldsh, baseb, atab + 13*92, atab + 14*92, ed, zA, zB);
        mixc2<3>(zA, zB, wt2 + 3*128, pwT, outa);
        conv1c(ldsh, baseb, atab + 15*92, ed, zA);
        conv2r(ldsh, baseb, atab + 12*92, atab + 0*92, ed, zB);
        mix_cr<0,3>(zA, zB, wt2 + 3*128, pwT, outa);           // h15 + h12
        mixr<2,0,true>(zB, wt2 + 0*128, cw2, cb, ldsh, baseb, pwT, outa);  // h0
    } else {
        // n=2: h7,h8 (complex pair), h6 (real); n=1: h3 (complex) + h2 (real)
        conv2c(ldsh, baseb, atab + 7*92, atab + 8*92, ed, zA, zB);
        mixc2<2>(zA, zB, wt2 + 2*128, pwT, outa);
        conv2r(ldsh, baseb, atab + 6*92, atab + 2*92, ed, zA);
        conv1c(ldsh, baseb, atab + 3*92, ed, zB);
        mix_cr<2,1>(zB, zA, wt2 + 1*128, pwT, outa);           // h3 + h2
        mixr<0,2,false>(zA, wt2 + 2*128, cw2, cb, ldsh, baseb, pwT, outa); // h6
    }

    // merge halves through LDS (x-tile is dead now); stride 33 avoids conflicts
    __syncthreads();
    float* lmerge = (float*)ldsh;
    if (hf == 1) {
#pragma unroll
        for (int k = 0; k < 16; ++k) {
            lmerge[vid*33 + 2*k]     = outa[k].x;
            lmerge[vid*33 + 2*k + 1] = outa[k].y;
        }
    }
    __syncthreads();
    if (hf == 0) {
        const int gz = z0 + tz, gy = y0 + ty, gx = x0 + tx;
#pragma unroll
        for (int k = 0; k < 16; ++k) {
            float v0 = obase[2*k]   + outa[k].x + lmerge[vid*33 + 2*k];
            float v1 = obase[2*k+1] + outa[k].y + lmerge[vid*33 + 2*k + 1];
            out[(((2*k)*48   + gz)*48 + gy)*48 + gx] = fmaxf(v0, 0.f);
            out[(((2*k+1)*48 + gz)*48 + gy)*48 + gx] = fmaxf(v1, 0.f);
        }
    }
}

extern "C" void kernel_launch(void* const* d_in, const int* in_sizes, int n_in,
                              void* d_out, int out_size, void* d_ws, size_t ws_size,
                              hipStream_t stream) {
    const float* x  = (const float*)d_in[0];
    const float* w  = (const float*)d_in[1];
    const float* cw = (const float*)d_in[2];
    const float* cb = (const float*)d_in[3];
    const float* sb = (const float*)d_in[4];
    const float* pw = (const float*)d_in[5];
    const float* pb = (const float*)d_in[6];
    float* out = (float*)d_out;
    char* wsb = (char*)d_ws;

    ssh_init<<<dim3(1), dim3(256), 0, stream>>>(w, cw, pw, sb, pb, wsb);
    ssh_main<<<dim3(48/TX, 48/TY, 48/TZ), dim3(256), 0, stream>>>(x, cb, wsb, out);
}